// Round 1
// baseline (1789.280 us; speedup 1.0000x reference)
//
#include <hip/hip_runtime.h>
#include <math.h>

#define HH 96
#define WW 96
#define LL 9216          // H*W
#define D9 288           // 32 q-channels * 9 taps
#define TOPK 5
#define QB 24            // queries per block (LL % QB == 0 -> 384 blocks/split)
#define KSPLIT 2
#define KPS (LL / KSPLIT)

__device__ __forceinline__ bool better(float av, int ai, float bv, int bi) {
    // descending by value, ties -> lower index (matches lax.top_k)
    return (av > bv) || (av == bv && ai < bi);
}

__device__ __forceinline__ void insert5(float (&v)[TOPK], int (&ix)[TOPK], float nv, int ni) {
    if (better(nv, ni, v[TOPK-1], ix[TOPK-1])) {
        v[TOPK-1] = nv; ix[TOPK-1] = ni;
        #pragma unroll
        for (int s = TOPK-1; s > 0; --s) {
            if (better(v[s], ix[s], v[s-1], ix[s-1])) {
                float tv = v[s]; v[s] = v[s-1]; v[s-1] = tv;
                int ti = ix[s]; ix[s] = ix[s-1]; ix[s-1] = ti;
            }
        }
    }
}

// ---------------- direct 3x3 SAME conv (cross-correlation, NCHW/OIHW) ----------------
__global__ __launch_bounds__(256) void conv3_kernel(
    const float* __restrict__ in, const float* __restrict__ Wt,
    const float* __restrict__ bias, float* __restrict__ out,
    int Cin, int doRelu)
{
    int co  = blockIdx.y;
    int pix = blockIdx.x * 256 + threadIdx.x;   // 36*256 == 9216 exactly
    int y = pix / WW, x = pix % WW;
    float acc = bias[co];
    const float* wb = Wt + (size_t)co * Cin * 9;
    for (int ci = 0; ci < Cin; ++ci) {
        const float* xp = in + (size_t)ci * LL;
        const float* wp = wb + ci * 9;
        #pragma unroll
        for (int u = 0; u < 3; ++u) {
            int yy = y + u - 1;
            bool yok = (unsigned)yy < (unsigned)HH;
            const float* row = xp + yy * WW;
            #pragma unroll
            for (int v = 0; v < 3; ++v) {
                int xx = x + v - 1;
                float val = (yok && (unsigned)xx < (unsigned)WW) ? row[xx] : 0.0f;
                acc = fmaf(val, wp[u*3+v], acc);
            }
        }
    }
    if (doRelu) acc = fmaxf(acc, 0.0f);
    out[(size_t)co * LL + pix] = acc;
}

// ------------- unfold3 + L2-normalize columns; write transposed [288][L] -------------
// ilv==0: plain outT[d*L + l]   (for q)
// ilv==1: 4-d-interleaved: outT[(d>>2)*4*L + 4*l + (d&3)]  (for k; float4 loads in topk)
__global__ __launch_bounds__(256) void unfold_norm_kernel(
    const float* __restrict__ in, float* __restrict__ outT, int ilv)
{
    int l = blockIdx.x * 256 + threadIdx.x;
    int y = l / WW, x = l % WW;
    float ss = 0.0f;
    #pragma unroll 1
    for (int c = 0; c < 32; ++c) {
        const float* xp = in + (size_t)c * LL;
        #pragma unroll
        for (int u = 0; u < 3; ++u) {
            int yy = y + u - 1;
            bool yok = (unsigned)yy < 96u;
            #pragma unroll
            for (int v = 0; v < 3; ++v) {
                int xx = x + v - 1;
                float val = (yok && (unsigned)xx < 96u) ? xp[yy*96+xx] : 0.0f;
                ss = fmaf(val, val, ss);
            }
        }
    }
    float inv = 1.0f / fmaxf(sqrtf(ss), 1e-12f);
    #pragma unroll 1
    for (int c = 0; c < 32; ++c) {
        const float* xp = in + (size_t)c * LL;
        #pragma unroll
        for (int u = 0; u < 3; ++u) {
            int yy = y + u - 1;
            bool yok = (unsigned)yy < 96u;
            #pragma unroll
            for (int v = 0; v < 3; ++v) {
                int xx = x + v - 1;
                float val = (yok && (unsigned)xx < 96u) ? xp[yy*96+xx] : 0.0f;
                int d = c*9 + u*3 + v;
                float o = val * inv;
                if (ilv) outT[(size_t)(d >> 2) * (4*LL) + ((size_t)l << 2) + (d & 3)] = o;
                else     outT[(size_t)d * LL + l] = o;
            }
        }
    }
}

// ---------------- fused similarity GEMM + streaming per-query top-5 ----------------
// grid = (LL/QB)*KSPLIT blocks; block handles QB queries x KPS keys.
__global__ __launch_bounds__(256, 3) void topk_kernel(
    const float* __restrict__ qnT, const float* __restrict__ knT4,
    float* __restrict__ valsS, int* __restrict__ idxsS)
{
    __shared__ alignas(16) float qtile[QB * D9];   // 27648 B
    __shared__ alignas(16) float Rtile[QB * 256];  // 24576 B (reused as merge buffer)
    int tid = threadIdx.x;
    int qb    = blockIdx.x >> 1;
    int split = blockIdx.x & 1;
    int q0   = qb * QB;
    int key0 = split * KPS;

    for (int e = tid; e < QB * D9; e += 256) {
        int qi = e / D9, d = e % D9;
        qtile[e] = qnT[(size_t)d * LL + q0 + qi];
    }
    __syncthreads();

    float lv[QB/4][TOPK]; int li[QB/4][TOPK];      // each wave owns QB/4 queries
    #pragma unroll
    for (int t = 0; t < QB/4; ++t)
        #pragma unroll
        for (int s = 0; s < TOPK; ++s) { lv[t][s] = -INFINITY; li[t][s] = 0x7fffffff; }

    int wave = tid >> 6, lane = tid & 63;
    const float4* kn4 = (const float4*)knT4;
    const float4* qt4 = (const float4*)qtile;

    for (int kb = 0; kb < KPS; kb += 256) {
        int l = key0 + kb + tid;                   // this thread's key
        float acc[QB];
        #pragma unroll
        for (int qi = 0; qi < QB; ++qi) acc[qi] = 0.0f;
        #pragma unroll 2
        for (int dg = 0; dg < D9/4; ++dg) {
            float4 kv = kn4[(size_t)dg * LL + l];  // coalesced 16B/lane
            #pragma unroll
            for (int qi = 0; qi < QB; ++qi) {
                float4 qv = qt4[qi * (D9/4) + dg]; // LDS broadcast
                acc[qi] = fmaf(kv.x, qv.x, acc[qi]);
                acc[qi] = fmaf(kv.y, qv.y, acc[qi]);
                acc[qi] = fmaf(kv.z, qv.z, acc[qi]);
                acc[qi] = fmaf(kv.w, qv.w, acc[qi]);
            }
        }
        #pragma unroll
        for (int qi = 0; qi < QB; ++qi) Rtile[qi * 256 + tid] = acc[qi];
        __syncthreads();
        #pragma unroll
        for (int t = 0; t < QB/4; ++t) {
            int qi = wave * (QB/4) + t;
            #pragma unroll
            for (int p = 0; p < 4; ++p) {
                float v  = Rtile[qi * 256 + p * 64 + lane];
                int   ki = key0 + kb + p * 64 + lane;
                insert5(lv[t], li[t], v, ki);
            }
        }
        __syncthreads();
    }

    // per-wave merge of 64 lanes' top-5 -> query top-5 (reuse Rtile as buffer)
    float* mv = Rtile;
    int*   mi = (int*)(Rtile + 256 * TOPK);
    #pragma unroll
    for (int t = 0; t < QB/4; ++t) {
        #pragma unroll
        for (int s = 0; s < TOPK; ++s) { mv[tid*TOPK+s] = lv[t][s]; mi[tid*TOPK+s] = li[t][s]; }
        __syncthreads();
        if (lane == 0) {
            float bv[TOPK]; int bi[TOPK];
            #pragma unroll
            for (int s = 0; s < TOPK; ++s) { bv[s] = -INFINITY; bi[s] = 0x7fffffff; }
            for (int j = 0; j < 64; ++j) {
                #pragma unroll
                for (int s = 0; s < TOPK; ++s)
                    insert5(bv, bi, mv[(wave*64+j)*TOPK+s], mi[(wave*64+j)*TOPK+s]);
            }
            int m = q0 + wave * (QB/4) + t;
            #pragma unroll
            for (int s = 0; s < TOPK; ++s) {
                valsS[(size_t)(split*TOPK + s) * LL + m] = bv[s];
                idxsS[(size_t)(split*TOPK + s) * LL + m] = bi[s];
            }
        }
        __syncthreads();
    }
}

// ---------------- merge the two key-splits' sorted top-5 lists ----------------
__global__ __launch_bounds__(256) void merge_topk_kernel(
    const float* __restrict__ valsS, const int* __restrict__ idxsS,
    float* __restrict__ vals, int* __restrict__ idxs)
{
    int m = blockIdx.x * 256 + threadIdx.x;
    float bv[TOPK]; int bi[TOPK];
    #pragma unroll
    for (int s = 0; s < TOPK; ++s) { bv[s] = -INFINITY; bi[s] = 0x7fffffff; }
    #pragma unroll
    for (int sp = 0; sp < KSPLIT; ++sp)
        #pragma unroll
        for (int s = 0; s < TOPK; ++s)
            insert5(bv, bi, valsS[(size_t)(sp*TOPK+s)*LL + m], idxsS[(size_t)(sp*TOPK+s)*LL + m]);
    #pragma unroll
    for (int s = 0; s < TOPK; ++s) {
        vals[(size_t)s*LL + m] = bv[s];
        idxs[(size_t)s*LL + m] = bi[s];
    }
}

// ------------- epilogue: gather(top-k idx) -> fold/9 -> *S, sum/4, + feat + x -------------
__global__ __launch_bounds__(256) void gather_out_kernel(
    const float* __restrict__ x, const float* __restrict__ feat,
    const float* __restrict__ vals, const int* __restrict__ idxs,
    float* __restrict__ out)
{
    int t = blockIdx.x * 256 + threadIdx.x;     // 64*9216 threads
    int c = t / LL, pix = t - c * LL;
    int y = pix / WW, x0 = pix - y * WW;
    const float* xc = x + (size_t)c * LL;
    float acc = 0.0f;
    #pragma unroll 1
    for (int s = 1; s < TOPK; ++s) {
        float S = vals[(size_t)s * LL + pix];
        float sum = 0.0f;
        #pragma unroll
        for (int i = 0; i < 3; ++i) {
            int qy = y + 1 - i;
            #pragma unroll
            for (int j = 0; j < 3; ++j) {
                int qx = x0 + 1 - j;
                if ((unsigned)qy < 96u && (unsigned)qx < 96u) {
                    int l = idxs[(size_t)s * LL + qy * WW + qx];
                    int yl = l / WW, xl = l - yl * WW;
                    int sy = yl + i - 1, sx = xl + j - 1;
                    if ((unsigned)sy < 96u && (unsigned)sx < 96u)
                        sum += xc[sy * WW + sx];
                }
            }
        }
        acc = fmaf(S, sum * (1.0f/9.0f), acc);
    }
    out[t] = feat[t] + xc[pix] + acc * 0.25f;
}

extern "C" void kernel_launch(void* const* d_in, const int* in_sizes, int n_in,
                              void* d_out, int out_size, void* d_ws, size_t ws_size,
                              hipStream_t stream)
{
    (void)in_sizes; (void)n_in; (void)out_size; (void)ws_size;
    const float* x  = (const float*)d_in[0];
    const float* W1 = (const float*)d_in[1];
    const float* b1 = (const float*)d_in[2];
    const float* W2 = (const float*)d_in[3];
    const float* b2 = (const float*)d_in[4];
    const float* Wq = (const float*)d_in[5];
    const float* bq = (const float*)d_in[6];
    const float* Wk = (const float*)d_in[7];
    const float* bk = (const float*)d_in[8];
    float* out = (float*)d_out;

    float* p = (float*)d_ws;                      // ~31 MB total scratch
    float* c1    = p; p += (size_t)64 * LL;
    float* feat  = p; p += (size_t)64 * LL;
    float* qq    = p; p += (size_t)32 * LL;
    float* kk    = p; p += (size_t)32 * LL;
    float* qnT   = p; p += (size_t)D9 * LL;       // [288][L]
    float* knT   = p; p += (size_t)D9 * LL;       // 4-d-interleaved
    float* valsS = p; p += (size_t)KSPLIT * TOPK * LL;
    int*   idxsS = (int*)p; p += (size_t)KSPLIT * TOPK * LL;
    float* vals  = p; p += (size_t)TOPK * LL;
    int*   idxs  = (int*)p; p += (size_t)TOPK * LL;

    conv3_kernel<<<dim3(36, 64), 256, 0, stream>>>(x,  W1, b1, c1,   64, 1);
    conv3_kernel<<<dim3(36, 64), 256, 0, stream>>>(c1, W2, b2, feat, 64, 1);
    conv3_kernel<<<dim3(36, 32), 256, 0, stream>>>(x,  Wq, bq, qq,   64, 0);
    conv3_kernel<<<dim3(36, 32), 256, 0, stream>>>(x,  Wk, bk, kk,   64, 0);
    unfold_norm_kernel<<<36, 256, 0, stream>>>(qq, qnT, 0);
    unfold_norm_kernel<<<36, 256, 0, stream>>>(kk, knT, 1);
    topk_kernel<<<(LL/QB)*KSPLIT, 256, 0, stream>>>(qnT, knT, valsS, idxsS);
    merge_topk_kernel<<<36, 256, 0, stream>>>(valsS, idxsS, vals, idxs);
    gather_out_kernel<<<(64*LL)/256, 256, 0, stream>>>(x, feat, vals, idxs, out);
}

// Round 2
// 838.883 us; speedup vs baseline: 2.1329x; 2.1329x over previous
//
#include <hip/hip_runtime.h>
#include <math.h>

#define HH 96
#define WW 96
#define LL 9216          // H*W
#define D9 288           // 32 q-channels * 9 taps
#define TOPK 5
#define NK 6             // per-split list length (margin for candidates)
#define NCAND 8          // fp32 re-rank candidates
#define KSPLIT 32
#define KEYS_PER_SPLIT (LL / KSPLIT)     // 288
#define PASSES (KEYS_PER_SPLIT / 32)     // 9
#define CHUNKS (32 * 36)                 // 16B chunks per 32-key pass (row=576B=36 chunks)
#define KROW 292                         // LDS row stride in bf16 elements (584B: 2-way banks, 8B aligned)

typedef short short8 __attribute__((ext_vector_type(8)));
typedef float f32x16 __attribute__((ext_vector_type(16)));

__device__ __forceinline__ unsigned short f2bf(float f) {
    union { float f; unsigned u; } a; a.f = f;
    unsigned r = a.u + 0x7fff + ((a.u >> 16) & 1);   // RNE
    return (unsigned short)(r >> 16);
}

template<int N>
__device__ __forceinline__ void insert_nt(float (&v)[N], int (&ix)[N], float nv, int ni) {
    if (nv > v[N-1]) {
        v[N-1] = nv; ix[N-1] = ni;
        #pragma unroll
        for (int s = N-1; s > 0; --s) {
            if (v[s] > v[s-1]) {
                float tv = v[s]; v[s] = v[s-1]; v[s-1] = tv;
                int ti = ix[s]; ix[s] = ix[s-1]; ix[s-1] = ti;
            }
        }
    }
}

__device__ __forceinline__ bool better_tb(float av, int ai, float bv, int bi) {
    return (av > bv) || (av == bv && ai < bi);
}

template<int N>
__device__ __forceinline__ void insert_tb(float (&v)[N], int (&ix)[N], float nv, int ni) {
    if (better_tb(nv, ni, v[N-1], ix[N-1])) {
        v[N-1] = nv; ix[N-1] = ni;
        #pragma unroll
        for (int s = N-1; s > 0; --s) {
            if (better_tb(v[s], ix[s], v[s-1], ix[s-1])) {
                float tv = v[s]; v[s] = v[s-1]; v[s-1] = tv;
                int ti = ix[s]; ix[s] = ix[s-1]; ix[s-1] = ti;
            }
        }
    }
}

// ---------------- direct 3x3 SAME conv (cross-correlation, NCHW/OIHW) ----------------
__global__ __launch_bounds__(256) void conv3_kernel(
    const float* __restrict__ in, const float* __restrict__ Wt,
    const float* __restrict__ bias, float* __restrict__ out,
    int Cin, int doRelu)
{
    int co  = blockIdx.y;
    int pix = blockIdx.x * 256 + threadIdx.x;   // 36*256 == 9216 exactly
    int y = pix / WW, x = pix % WW;
    float acc = bias[co];
    const float* wb = Wt + (size_t)co * Cin * 9;
    for (int ci = 0; ci < Cin; ++ci) {
        const float* xp = in + (size_t)ci * LL;
        const float* wp = wb + ci * 9;
        #pragma unroll
        for (int u = 0; u < 3; ++u) {
            int yy = y + u - 1;
            bool yok = (unsigned)yy < (unsigned)HH;
            const float* row = xp + yy * WW;
            #pragma unroll
            for (int v = 0; v < 3; ++v) {
                int xx = x + v - 1;
                float val = (yok && (unsigned)xx < (unsigned)WW) ? row[xx] : 0.0f;
                acc = fmaf(val, wp[u*3+v], acc);
            }
        }
    }
    if (doRelu) acc = fmaxf(acc, 0.0f);
    out[(size_t)co * LL + pix] = acc;
}

// ------ unfold3 + L2-normalize columns; row-major [L][288] in fp32 AND bf16 ------
__global__ __launch_bounds__(256) void unfold_norm_rm_kernel(
    const float* __restrict__ in, float* __restrict__ out_f32,
    unsigned short* __restrict__ out_bf)
{
    int l = blockIdx.x * 256 + threadIdx.x;
    int y = l / WW, x = l % WW;
    float ss = 0.0f;
    #pragma unroll 1
    for (int c = 0; c < 32; ++c) {
        const float* xp = in + (size_t)c * LL;
        #pragma unroll
        for (int u = 0; u < 3; ++u) {
            int yy = y + u - 1;
            bool yok = (unsigned)yy < 96u;
            #pragma unroll
            for (int v = 0; v < 3; ++v) {
                int xx = x + v - 1;
                float val = (yok && (unsigned)xx < 96u) ? xp[yy*96+xx] : 0.0f;
                ss = fmaf(val, val, ss);
            }
        }
    }
    float inv = 1.0f / fmaxf(sqrtf(ss), 1e-12f);
    float* orow = out_f32 + (size_t)l * D9;
    unsigned short* brow = out_bf + (size_t)l * D9;
    #pragma unroll 1
    for (int c = 0; c < 32; ++c) {
        const float* xp = in + (size_t)c * LL;
        #pragma unroll
        for (int u = 0; u < 3; ++u) {
            int yy = y + u - 1;
            bool yok = (unsigned)yy < 96u;
            #pragma unroll
            for (int v = 0; v < 3; ++v) {
                int xx = x + v - 1;
                float val = (yok && (unsigned)xx < 96u) ? xp[yy*96+xx] : 0.0f;
                float o = val * inv;
                int d = c*9 + u*3 + v;
                orow[d] = o;
                brow[d] = f2bf(o);
            }
        }
    }
}

// ---------------- MFMA similarity + streaming per-query top-6 per key-split ----------------
// Block: 4 waves, 256 queries (wave w: queries qtile*256 + w*64 + bset*32 + (lane&31)).
// Keys: 288 per split, staged 32/pass into double-buffered LDS.
__global__ __launch_bounds__(256, 2) void topk_mfma_kernel(
    const unsigned short* __restrict__ qn_bf, const unsigned short* __restrict__ kn_bf,
    float* __restrict__ valsS, int* __restrict__ idxsS)
{
    __shared__ unsigned short ks[2][32 * KROW];       // 2 * 18688 B

    int tid  = threadIdx.x;
    int wave = tid >> 6, lane = tid & 63;
    int col = lane & 31, khalf = lane >> 5;
    int qtile = blockIdx.x >> 5;
    int split = blockIdx.x & 31;
    int q0w = qtile * 256 + wave * 64;
    int key0 = split * KEYS_PER_SPLIT;

    // ---- load q fragments for both 32-query sets, full K=288, into registers ----
    short8 qf[2][18];
    #pragma unroll
    for (int b = 0; b < 2; ++b) {
        const unsigned short* qrow = qn_bf + (size_t)(q0w + b*32 + col) * D9 + khalf * 8;
        #pragma unroll
        for (int dg = 0; dg < 18; ++dg)
            qf[b][dg] = *(const short8*)(qrow + dg * 16);
    }

    float lv[2][NK]; int li[2][NK];
    #pragma unroll
    for (int b = 0; b < 2; ++b)
        #pragma unroll
        for (int s = 0; s < NK; ++s) { lv[b][s] = -INFINITY; li[b][s] = 0x7fffffff; }

    const char* kg = (const char*)kn_bf;
    uint4 pre[5];

    // prefetch pass 0
    #pragma unroll
    for (int c0 = 0; c0 < 5; ++c0) {
        int c = tid + c0 * 256;
        if (c < CHUNKS) {
            int key = c / 36, off = c - key * 36;
            pre[c0] = *(const uint4*)(kg + (size_t)(key0 + key) * 576 + off * 16);
        }
    }
    // store pass 0 -> buf 0
    #pragma unroll
    for (int c0 = 0; c0 < 5; ++c0) {
        int c = tid + c0 * 256;
        if (c < CHUNKS) {
            int key = c / 36, off = c - key * 36;
            char* d = (char*)ks[0] + key * (KROW*2) + off * 16;
            *(uint2*)d       = *(uint2*)&pre[c0];
            *(uint2*)(d + 8) = *((uint2*)&pre[c0] + 1);
        }
    }
    __syncthreads();

    for (int p = 0; p < PASSES; ++p) {
        // prefetch next pass (global -> regs), overlaps with compute
        if (p + 1 < PASSES) {
            #pragma unroll
            for (int c0 = 0; c0 < 5; ++c0) {
                int c = tid + c0 * 256;
                if (c < CHUNKS) {
                    int key = c / 36, off = c - key * 36;
                    pre[c0] = *(const uint4*)(kg + (size_t)(key0 + (p+1)*32 + key) * 576 + off * 16);
                }
            }
        }

        // ---- compute 32 keys x 64 queries for this wave ----
        f32x16 acc0 = {}, acc1 = {};
        const char* kb = (const char*)ks[p & 1] + (size_t)col * (KROW*2) + khalf * 16;
        #pragma unroll
        for (int dg = 0; dg < 18; ++dg) {
            short8 af;
            *(uint2*)&af       = *(const uint2*)(kb + dg * 32);
            *((uint2*)&af + 1) = *(const uint2*)(kb + dg * 32 + 8);
            acc0 = __builtin_amdgcn_mfma_f32_32x32x16_bf16(af, qf[0][dg], acc0, 0, 0, 0);
            acc1 = __builtin_amdgcn_mfma_f32_32x32x16_bf16(af, qf[1][dg], acc1, 0, 0, 0);
        }

        // ---- streaming top-6 update (no tie-break; fp32 re-rank fixes ordering) ----
        int kbase = key0 + p * 32 + 4 * khalf;
        #pragma unroll
        for (int r = 0; r < 16; ++r) {
            int key = kbase + (r & 3) + 8 * (r >> 2);
            insert_nt<NK>(lv[0], li[0], acc0[r], key);
            insert_nt<NK>(lv[1], li[1], acc1[r], key);
        }

        // write next pass to other LDS buffer
        if (p + 1 < PASSES) {
            #pragma unroll
            for (int c0 = 0; c0 < 5; ++c0) {
                int c = tid + c0 * 256;
                if (c < CHUNKS) {
                    int key = c / 36, off = c - key * 36;
                    char* d = (char*)ks[(p+1) & 1] + key * (KROW*2) + off * 16;
                    *(uint2*)d       = *(uint2*)&pre[c0];
                    *(uint2*)(d + 8) = *((uint2*)&pre[c0] + 1);
                }
            }
        }
        __syncthreads();
    }

    // ---- merge lane pair (lane, lane^32): same query, disjoint keys ----
    #pragma unroll
    for (int b = 0; b < 2; ++b) {
        float pv[NK]; int pi[NK];
        #pragma unroll
        for (int s = 0; s < NK; ++s) {
            pv[s] = __shfl_xor(lv[b][s], 32);
            pi[s] = __shfl_xor(li[b][s], 32);
        }
        #pragma unroll
        for (int s = 0; s < NK; ++s) insert_nt<NK>(lv[b], li[b], pv[s], pi[s]);
        if (lane < 32) {
            int q = q0w + b * 32 + col;
            #pragma unroll
            for (int s = 0; s < NK; ++s) {
                valsS[(size_t)(split * NK + s) * LL + q] = lv[b][s];
                idxsS[(size_t)(split * NK + s) * LL + q] = li[b][s];
            }
        }
    }
}

// -------- merge 32 splits -> top-8 candidates -> exact fp32 re-rank -> top-5 --------
// 8 threads per query; grid = LL/32 blocks of 256.
__global__ __launch_bounds__(256) void rerank_kernel(
    const float* __restrict__ valsS, const int* __restrict__ idxsS,
    const float* __restrict__ qn_f32, const float* __restrict__ kn_f32,
    float* __restrict__ vals, int* __restrict__ idxs)
{
    int tid = threadIdx.x;
    int q = blockIdx.x * 32 + (tid >> 3);
    int c = tid & 7;

    float cv[NCAND]; int ci[NCAND];
    #pragma unroll
    for (int s = 0; s < NCAND; ++s) { cv[s] = -INFINITY; ci[s] = 0; }
    #pragma unroll 1
    for (int sp = 0; sp < KSPLIT; ++sp)
        #pragma unroll
        for (int s = 0; s < NK; ++s)
            insert_nt<NCAND>(cv, ci, valsS[(size_t)(sp * NK + s) * LL + q],
                                     idxsS[(size_t)(sp * NK + s) * LL + q]);

    // exact fp32 dot for this thread's candidate
    int l = ci[c];
    const float4* qr = (const float4*)(qn_f32 + (size_t)q * D9);
    const float4* kr = (const float4*)(kn_f32 + (size_t)l * D9);
    float s0 = 0.f, s1 = 0.f, s2 = 0.f, s3 = 0.f;
    #pragma unroll 6
    for (int i = 0; i < D9/4; ++i) {
        float4 a = qr[i], b = kr[i];
        s0 = fmaf(a.x, b.x, s0); s1 = fmaf(a.y, b.y, s1);
        s2 = fmaf(a.z, b.z, s2); s3 = fmaf(a.w, b.w, s3);
    }
    float sc = (s0 + s1) + (s2 + s3);

    float bv[TOPK]; int bi[TOPK];
    #pragma unroll
    for (int s = 0; s < TOPK; ++s) { bv[s] = -INFINITY; bi[s] = 0x7fffffff; }
    int base = tid & ~7;
    #pragma unroll
    for (int cc = 0; cc < NCAND; ++cc) {
        float sv = __shfl(sc, base + cc);
        insert_tb<TOPK>(bv, bi, sv, ci[cc]);   // ci identical across the 8 threads
    }
    if (c == 0) {
        #pragma unroll
        for (int s = 0; s < TOPK; ++s) {
            vals[(size_t)s * LL + q] = bv[s];
            idxs[(size_t)s * LL + q] = bi[s];
        }
    }
}

// ------------- epilogue: gather(top-k idx) -> fold/9 -> *S, sum/4, + feat + x -------------
__global__ __launch_bounds__(256) void gather_out_kernel(
    const float* __restrict__ x, const float* __restrict__ feat,
    const float* __restrict__ vals, const int* __restrict__ idxs,
    float* __restrict__ out)
{
    int t = blockIdx.x * 256 + threadIdx.x;     // 64*9216 threads
    int c = t / LL, pix = t - c * LL;
    int y = pix / WW, x0 = pix - y * WW;
    const float* xc = x + (size_t)c * LL;
    float acc = 0.0f;
    #pragma unroll 1
    for (int s = 1; s < TOPK; ++s) {
        float S = vals[(size_t)s * LL + pix];
        float sum = 0.0f;
        #pragma unroll
        for (int i = 0; i < 3; ++i) {
            int qy = y + 1 - i;
            #pragma unroll
            for (int j = 0; j < 3; ++j) {
                int qx = x0 + 1 - j;
                if ((unsigned)qy < 96u && (unsigned)qx < 96u) {
                    int l = idxs[(size_t)s * LL + qy * WW + qx];
                    int yl = l / WW, xl = l - yl * WW;
                    int sy = yl + i - 1, sx = xl + j - 1;
                    if ((unsigned)sy < 96u && (unsigned)sx < 96u)
                        sum += xc[sy * WW + sx];
                }
            }
        }
        acc = fmaf(S, sum * (1.0f/9.0f), acc);
    }
    out[t] = feat[t] + xc[pix] + acc * 0.25f;
}

extern "C" void kernel_launch(void* const* d_in, const int* in_sizes, int n_in,
                              void* d_out, int out_size, void* d_ws, size_t ws_size,
                              hipStream_t stream)
{
    (void)in_sizes; (void)n_in; (void)out_size; (void)ws_size;
    const float* x  = (const float*)d_in[0];
    const float* W1 = (const float*)d_in[1];
    const float* b1 = (const float*)d_in[2];
    const float* W2 = (const float*)d_in[3];
    const float* b2 = (const float*)d_in[4];
    const float* Wq = (const float*)d_in[5];
    const float* bq = (const float*)d_in[6];
    const float* Wk = (const float*)d_in[7];
    const float* bk = (const float*)d_in[8];
    float* out = (float*)d_out;

    char* p = (char*)d_ws;
    float* c1     = (float*)p;            p += (size_t)64 * LL * 4;
    float* feat   = (float*)p;            p += (size_t)64 * LL * 4;
    float* qq     = (float*)p;            p += (size_t)32 * LL * 4;
    float* kk     = (float*)p;            p += (size_t)32 * LL * 4;
    float* qn_f32 = (float*)p;            p += (size_t)LL * D9 * 4;
    float* kn_f32 = (float*)p;            p += (size_t)LL * D9 * 4;
    unsigned short* qn_bf = (unsigned short*)p;  p += (size_t)LL * D9 * 2;
    unsigned short* kn_bf = (unsigned short*)p;  p += (size_t)LL * D9 * 2;
    float* valsS  = (float*)p;            p += (size_t)KSPLIT * NK * LL * 4;
    int*   idxsS  = (int*)p;              p += (size_t)KSPLIT * NK * LL * 4;
    float* vals   = (float*)p;            p += (size_t)TOPK * LL * 4;
    int*   idxs   = (int*)p;              p += (size_t)TOPK * LL * 4;

    conv3_kernel<<<dim3(36, 64), 256, 0, stream>>>(x,  W1, b1, c1,   64, 1);
    conv3_kernel<<<dim3(36, 64), 256, 0, stream>>>(c1, W2, b2, feat, 64, 1);
    conv3_kernel<<<dim3(36, 32), 256, 0, stream>>>(x,  Wq, bq, qq,   64, 0);
    conv3_kernel<<<dim3(36, 32), 256, 0, stream>>>(x,  Wk, bk, kk,   64, 0);
    unfold_norm_rm_kernel<<<36, 256, 0, stream>>>(qq, qn_f32, qn_bf);
    unfold_norm_rm_kernel<<<36, 256, 0, stream>>>(kk, kn_f32, kn_bf);
    topk_mfma_kernel<<<36 * KSPLIT, 256, 0, stream>>>(qn_bf, kn_bf, valsS, idxsS);
    rerank_kernel<<<LL / 32, 256, 0, stream>>>(valsS, idxsS, qn_f32, kn_f32, vals, idxs);
    gather_out_kernel<<<(64 * LL) / 256, 256, 0, stream>>>(x, feat, vals, idxs, out);
}

// Round 3
// 515.630 us; speedup vs baseline: 3.4701x; 1.6269x over previous
//
#include <hip/hip_runtime.h>
#include <math.h>

#define HH 96
#define WW 96
#define LL 9216          // H*W
#define D9 288           // 32 q-channels * 9 taps
#define TOPK 5
#define NK 6             // per-split list length (margin for candidates)
#define NCAND 8          // fp32 re-rank candidates
#define KSPLIT 32
#define KEYS_PER_SPLIT (LL / KSPLIT)     // 288
#define PASSES (KEYS_PER_SPLIT / 32)     // 9
#define CHUNKS (32 * 36)                 // 16B chunks per 32-key pass (row=576B=36 chunks)
#define KROW 292                         // LDS row stride in bf16 elements (584B)

typedef short short8 __attribute__((ext_vector_type(8)));
typedef float f32x16 __attribute__((ext_vector_type(16)));

__device__ __forceinline__ float  asf(unsigned u) { union { unsigned u; float f; } a; a.u = u; return a.f; }
__device__ __forceinline__ unsigned asu(float f)  { union { float f; unsigned u; } a; a.f = f; return a.u; }

__device__ __forceinline__ unsigned short f2bf(float f) {
    unsigned u = asu(f);
    unsigned r = u + 0x7fff + ((u >> 16) & 1);   // RNE
    return (unsigned short)(r >> 16);
}

// branch-free insert into descending-sorted array of packed (score|key) floats
template<int N>
__device__ __forceinline__ void ins_packed(float (&v)[N], float x) {
    #pragma unroll
    for (int s = 0; s < N; ++s) {
        float hi = fmaxf(v[s], x);
        x = fminf(v[s], x);
        v[s] = hi;
    }
}

template<int N>
__device__ __forceinline__ void insert_nt(float (&v)[N], int (&ix)[N], float nv, int ni) {
    if (nv > v[N-1]) {
        v[N-1] = nv; ix[N-1] = ni;
        #pragma unroll
        for (int s = N-1; s > 0; --s) {
            if (v[s] > v[s-1]) {
                float tv = v[s]; v[s] = v[s-1]; v[s-1] = tv;
                int ti = ix[s]; ix[s] = ix[s-1]; ix[s-1] = ti;
            }
        }
    }
}

__device__ __forceinline__ bool better_tb(float av, int ai, float bv, int bi) {
    return (av > bv) || (av == bv && ai < bi);
}

template<int N>
__device__ __forceinline__ void insert_tb(float (&v)[N], int (&ix)[N], float nv, int ni) {
    if (better_tb(nv, ni, v[N-1], ix[N-1])) {
        v[N-1] = nv; ix[N-1] = ni;
        #pragma unroll
        for (int s = N-1; s > 0; --s) {
            if (better_tb(v[s], ix[s], v[s-1], ix[s-1])) {
                float tv = v[s]; v[s] = v[s-1]; v[s-1] = tv;
                int ti = ix[s]; ix[s] = ix[s-1]; ix[s-1] = ti;
            }
        }
    }
}

// ---------------- direct 3x3 SAME conv, 8 output channels per block ----------------
__global__ __launch_bounds__(256) void conv3_co8_kernel(
    const float* __restrict__ in, const float* __restrict__ Wt,
    const float* __restrict__ bias, float* __restrict__ out,
    int Cin, int doRelu)
{
    int co0 = blockIdx.y * 8;
    int pix = blockIdx.x * 256 + threadIdx.x;   // 36*256 == 9216
    int y = pix / WW, x = pix % WW;

    int  offs[9]; bool msk[9];
    #pragma unroll
    for (int u = 0; u < 3; ++u)
        #pragma unroll
        for (int v = 0; v < 3; ++v) {
            int yy = y + u - 1, xx = x + v - 1;
            bool ok = ((unsigned)yy < 96u) && ((unsigned)xx < 96u);
            msk[u*3+v]  = ok;
            offs[u*3+v] = ok ? (yy*96 + xx) : 0;
        }

    float acc[8];
    #pragma unroll
    for (int j = 0; j < 8; ++j) acc[j] = bias[co0 + j];

    #pragma unroll 2
    for (int ci = 0; ci < Cin; ++ci) {
        const float* xp = in + (size_t)ci * LL;
        float v9[9];
        #pragma unroll
        for (int t = 0; t < 9; ++t) v9[t] = msk[t] ? xp[offs[t]] : 0.0f;
        const float* wb = Wt + (size_t)co0 * Cin * 9 + ci * 9;
        #pragma unroll
        for (int j = 0; j < 8; ++j) {
            const float* wp = wb + (size_t)j * Cin * 9;
            #pragma unroll
            for (int t = 0; t < 9; ++t) acc[j] = fmaf(v9[t], wp[t], acc[j]);
        }
    }
    #pragma unroll
    for (int j = 0; j < 8; ++j) {
        float r = doRelu ? fmaxf(acc[j], 0.0f) : acc[j];
        out[(size_t)(co0 + j) * LL + pix] = r;
    }
}

// ---------------- fused q/k conv: 4 q-channels + 4 k-channels per block ----------------
__global__ __launch_bounds__(256) void convqk_kernel(
    const float* __restrict__ in,
    const float* __restrict__ Wq, const float* __restrict__ bq,
    const float* __restrict__ Wk, const float* __restrict__ bk,
    float* __restrict__ qq, float* __restrict__ kk)
{
    int co0 = blockIdx.y * 4;                   // 8 groups x 4 = 32 channels
    int pix = blockIdx.x * 256 + threadIdx.x;
    int y = pix / WW, x = pix % WW;

    int  offs[9]; bool msk[9];
    #pragma unroll
    for (int u = 0; u < 3; ++u)
        #pragma unroll
        for (int v = 0; v < 3; ++v) {
            int yy = y + u - 1, xx = x + v - 1;
            bool ok = ((unsigned)yy < 96u) && ((unsigned)xx < 96u);
            msk[u*3+v]  = ok;
            offs[u*3+v] = ok ? (yy*96 + xx) : 0;
        }

    float aq[4], ak[4];
    #pragma unroll
    for (int j = 0; j < 4; ++j) { aq[j] = bq[co0 + j]; ak[j] = bk[co0 + j]; }

    #pragma unroll 2
    for (int ci = 0; ci < 64; ++ci) {
        const float* xp = in + (size_t)ci * LL;
        float v9[9];
        #pragma unroll
        for (int t = 0; t < 9; ++t) v9[t] = msk[t] ? xp[offs[t]] : 0.0f;
        #pragma unroll
        for (int j = 0; j < 4; ++j) {
            const float* wpq = Wq + ((size_t)(co0 + j) * 64 + ci) * 9;
            const float* wpk = Wk + ((size_t)(co0 + j) * 64 + ci) * 9;
            #pragma unroll
            for (int t = 0; t < 9; ++t) {
                aq[j] = fmaf(v9[t], wpq[t], aq[j]);
                ak[j] = fmaf(v9[t], wpk[t], ak[j]);
            }
        }
    }
    #pragma unroll
    for (int j = 0; j < 4; ++j) {
        qq[(size_t)(co0 + j) * LL + pix] = aq[j];
        kk[(size_t)(co0 + j) * LL + pix] = ak[j];
    }
}

// ------ unfold3 + L2-normalize; row-major [L][288] fp32 + bf16, coalesced writes ------
// blockIdx.y: 0 -> q, 1 -> k. Block = 256 pixels.
__global__ __launch_bounds__(256) void unfold_norm_kernel(
    const float* __restrict__ q_in, float* __restrict__ q_f32, unsigned short* __restrict__ q_bf,
    const float* __restrict__ k_in, float* __restrict__ k_f32, unsigned short* __restrict__ k_bf)
{
    const float* in;
    float* out_f32; unsigned short* out_bf;
    if (blockIdx.y == 0) { in = q_in; out_f32 = q_f32; out_bf = q_bf; }
    else                 { in = k_in; out_f32 = k_f32; out_bf = k_bf; }

    __shared__ float inv_s[256];
    int tid = threadIdx.x;
    int pix0 = blockIdx.x * 256;

    // phase 1: per-pixel inverse norm
    {
        int l = pix0 + tid;
        int y = l / WW, x = l % WW;
        float ss = 0.0f;
        #pragma unroll 1
        for (int c = 0; c < 32; ++c) {
            const float* xp = in + (size_t)c * LL;
            #pragma unroll
            for (int u = 0; u < 3; ++u) {
                int yy = y + u - 1;
                bool yok = (unsigned)yy < 96u;
                #pragma unroll
                for (int v = 0; v < 3; ++v) {
                    int xx = x + v - 1;
                    float val = (yok && (unsigned)xx < 96u) ? xp[yy*96+xx] : 0.0f;
                    ss = fmaf(val, val, ss);
                }
            }
        }
        inv_s[tid] = 1.0f / fmaxf(sqrtf(ss), 1e-12f);
    }
    __syncthreads();

    // phase 2: 256 px * 72 float4-chunks, coalesced writes
    #pragma unroll 1
    for (int it = 0; it < 72; ++it) {
        int e = it * 256 + tid;
        int l_loc = e / 72, dc = e - l_loc * 72;
        int l = pix0 + l_loc;
        int y = l / WW, x = l % WW;
        float inv = inv_s[l_loc];
        float4 o;
        float* op = &o.x;
        #pragma unroll
        for (int i = 0; i < 4; ++i) {
            int d = dc * 4 + i;
            int c = d / 9, rm = d - c * 9;
            int u = rm / 3, v = rm - u * 3;
            int yy = y + u - 1, xx = x + v - 1;
            float val = ((unsigned)yy < 96u && (unsigned)xx < 96u)
                        ? in[(size_t)c * LL + yy*96 + xx] : 0.0f;
            op[i] = val * inv;
        }
        *(float4*)(out_f32 + (size_t)l * D9 + dc * 4) = o;
        unsigned short b4[4];
        #pragma unroll
        for (int i = 0; i < 4; ++i) b4[i] = f2bf(op[i]);
        *(uint2*)(out_bf + (size_t)l * D9 + dc * 4) = *(uint2*)b4;
    }
}

// ---------------- MFMA similarity + packed streaming top-6 per key-split ----------------
__global__ __launch_bounds__(256, 2) void topk_mfma_kernel(
    const unsigned short* __restrict__ qn_bf, const unsigned short* __restrict__ kn_bf,
    float* __restrict__ valsS, int* __restrict__ idxsS)
{
    __shared__ unsigned short ks[2][32 * KROW];       // 2 * 18688 B

    int tid  = threadIdx.x;
    int wave = tid >> 6, lane = tid & 63;
    int col = lane & 31, khalf = lane >> 5;
    int qtile = blockIdx.x >> 5;
    int split = blockIdx.x & 31;
    int q0w = qtile * 256 + wave * 64;
    int key0 = split * KEYS_PER_SPLIT;

    // q fragments: both 32-query sets, full K=288
    short8 qf[2][18];
    #pragma unroll
    for (int b = 0; b < 2; ++b) {
        const unsigned short* qrow = qn_bf + (size_t)(q0w + b*32 + col) * D9 + khalf * 8;
        #pragma unroll
        for (int dg = 0; dg < 18; ++dg)
            qf[b][dg] = *(const short8*)(qrow + dg * 16);
    }

    float lv0[NK], lv1[NK];
    #pragma unroll
    for (int s = 0; s < NK; ++s) { lv0[s] = -INFINITY; lv1[s] = -INFINITY; }

    const char* kg = (const char*)kn_bf;
    uint4 pre[5];

    #pragma unroll
    for (int c0 = 0; c0 < 5; ++c0) {
        int c = tid + c0 * 256;
        if (c < CHUNKS) {
            int key = c / 36, off = c - key * 36;
            pre[c0] = *(const uint4*)(kg + (size_t)(key0 + key) * 576 + off * 16);
        }
    }
    #pragma unroll
    for (int c0 = 0; c0 < 5; ++c0) {
        int c = tid + c0 * 256;
        if (c < CHUNKS) {
            int key = c / 36, off = c - key * 36;
            char* d = (char*)ks[0] + key * (KROW*2) + off * 16;
            *(uint2*)d       = *(uint2*)&pre[c0];
            *(uint2*)(d + 8) = *((uint2*)&pre[c0] + 1);
        }
    }
    __syncthreads();

    for (int p = 0; p < PASSES; ++p) {
        if (p + 1 < PASSES) {
            #pragma unroll
            for (int c0 = 0; c0 < 5; ++c0) {
                int c = tid + c0 * 256;
                if (c < CHUNKS) {
                    int key = c / 36, off = c - key * 36;
                    pre[c0] = *(const uint4*)(kg + (size_t)(key0 + (p+1)*32 + key) * 576 + off * 16);
                }
            }
        }

        f32x16 acc0 = {}, acc1 = {};
        const char* kb = (const char*)ks[p & 1] + (size_t)col * (KROW*2) + khalf * 16;
        #pragma unroll
        for (int dg = 0; dg < 18; ++dg) {
            short8 af;
            *(uint2*)&af       = *(const uint2*)(kb + dg * 32);
            *((uint2*)&af + 1) = *(const uint2*)(kb + dg * 32 + 8);
            acc0 = __builtin_amdgcn_mfma_f32_32x32x16_bf16(af, qf[0][dg], acc0, 0, 0, 0);
            acc1 = __builtin_amdgcn_mfma_f32_32x32x16_bf16(af, qf[1][dg], acc1, 0, 0, 0);
        }

        // pack (score | 9-bit local key), branch-free sorted insert
        int lbase = p * 32 + 4 * khalf;
        #pragma unroll
        for (int r = 0; r < 16; ++r) {
            unsigned lkey = (unsigned)(lbase + (r & 3) + 8 * (r >> 2));
            ins_packed<NK>(lv0, asf((asu(acc0[r]) & 0xFFFFFE00u) | lkey));
            ins_packed<NK>(lv1, asf((asu(acc1[r]) & 0xFFFFFE00u) | lkey));
        }

        if (p + 1 < PASSES) {
            #pragma unroll
            for (int c0 = 0; c0 < 5; ++c0) {
                int c = tid + c0 * 256;
                if (c < CHUNKS) {
                    int key = c / 36, off = c - key * 36;
                    char* d = (char*)ks[(p+1) & 1] + key * (KROW*2) + off * 16;
                    *(uint2*)d       = *(uint2*)&pre[c0];
                    *(uint2*)(d + 8) = *((uint2*)&pre[c0] + 1);
                }
            }
        }
        __syncthreads();
    }

    // merge lane pair (lane, lane^32): same query, disjoint keys; then write
    #pragma unroll
    for (int b = 0; b < 2; ++b) {
        float* lv = b ? lv1 : lv0;
        float pv[NK];
        #pragma unroll
        for (int s = 0; s < NK; ++s) pv[s] = __shfl_xor(lv[s], 32);
        #pragma unroll
        for (int s = 0; s < NK; ++s) {
            float x = pv[s];
            #pragma unroll
            for (int t = 0; t < NK; ++t) {
                float hi = fmaxf(lv[t], x);
                x = fminf(lv[t], x);
                lv[t] = hi;
            }
        }
        if (lane < 32) {
            int q = q0w + b * 32 + col;
            #pragma unroll
            for (int s = 0; s < NK; ++s) {
                unsigned u = asu(lv[s]);
                valsS[(size_t)(split * NK + s) * LL + q] = asf(u & 0xFFFFFE00u);
                idxsS[(size_t)(split * NK + s) * LL + q] = key0 + (int)(u & 0x1FFu);
            }
        }
    }
}

// -------- merge 32 splits -> top-8 candidates -> exact fp32 re-rank -> top-5 --------
__global__ __launch_bounds__(256) void rerank_kernel(
    const float* __restrict__ valsS, const int* __restrict__ idxsS,
    const float* __restrict__ qn_f32, const float* __restrict__ kn_f32,
    float* __restrict__ vals, int* __restrict__ idxs)
{
    int tid = threadIdx.x;
    int q = blockIdx.x * 32 + (tid >> 3);
    int c = tid & 7;

    float cv[NCAND]; int ci[NCAND];
    #pragma unroll
    for (int s = 0; s < NCAND; ++s) { cv[s] = -INFINITY; ci[s] = 0; }
    #pragma unroll 1
    for (int sp = 0; sp < KSPLIT; ++sp)
        #pragma unroll
        for (int s = 0; s < NK; ++s)
            insert_nt<NCAND>(cv, ci, valsS[(size_t)(sp * NK + s) * LL + q],
                                     idxsS[(size_t)(sp * NK + s) * LL + q]);

    int l = ci[c];
    const float4* qr = (const float4*)(qn_f32 + (size_t)q * D9);
    const float4* kr = (const float4*)(kn_f32 + (size_t)l * D9);
    float s0 = 0.f, s1 = 0.f, s2 = 0.f, s3 = 0.f;
    #pragma unroll 6
    for (int i = 0; i < D9/4; ++i) {
        float4 a = qr[i], b = kr[i];
        s0 = fmaf(a.x, b.x, s0); s1 = fmaf(a.y, b.y, s1);
        s2 = fmaf(a.z, b.z, s2); s3 = fmaf(a.w, b.w, s3);
    }
    float sc = (s0 + s1) + (s2 + s3);

    float bv[TOPK]; int bi[TOPK];
    #pragma unroll
    for (int s = 0; s < TOPK; ++s) { bv[s] = -INFINITY; bi[s] = 0x7fffffff; }
    int base = tid & ~7;
    #pragma unroll
    for (int cc = 0; cc < NCAND; ++cc) {
        float sv = __shfl(sc, base + cc);
        insert_tb<TOPK>(bv, bi, sv, ci[cc]);
    }
    if (c == 0) {
        #pragma unroll
        for (int s = 0; s < TOPK; ++s) {
            vals[(size_t)s * LL + q] = bv[s];
            idxs[(size_t)s * LL + q] = bi[s];
        }
    }
}

// ------------- epilogue: gather(top-k idx) -> fold/9 -> *S, sum/4, + feat + x -------------
__global__ __launch_bounds__(256) void gather_out_kernel(
    const float* __restrict__ x, const float* __restrict__ feat,
    const float* __restrict__ vals, const int* __restrict__ idxs,
    float* __restrict__ out)
{
    int t = blockIdx.x * 256 + threadIdx.x;
    int c = t / LL, pix = t - c * LL;
    int y = pix / WW, x0 = pix - y * WW;
    const float* xc = x + (size_t)c * LL;
    float acc = 0.0f;
    #pragma unroll 1
    for (int s = 1; s < TOPK; ++s) {
        float S = vals[(size_t)s * LL + pix];
        float sum = 0.0f;
        #pragma unroll
        for (int i = 0; i < 3; ++i) {
            int qy = y + 1 - i;
            #pragma unroll
            for (int j = 0; j < 3; ++j) {
                int qx = x0 + 1 - j;
                if ((unsigned)qy < 96u && (unsigned)qx < 96u) {
                    int l = idxs[(size_t)s * LL + qy * WW + qx];
                    int yl = l / WW, xl = l - yl * WW;
                    int sy = yl + i - 1, sx = xl + j - 1;
                    if ((unsigned)sy < 96u && (unsigned)sx < 96u)
                        sum += xc[sy * WW + sx];
                }
            }
        }
        acc = fmaf(S, sum * (1.0f/9.0f), acc);
    }
    out[t] = feat[t] + xc[pix] + acc * 0.25f;
}

extern "C" void kernel_launch(void* const* d_in, const int* in_sizes, int n_in,
                              void* d_out, int out_size, void* d_ws, size_t ws_size,
                              hipStream_t stream)
{
    (void)in_sizes; (void)n_in; (void)out_size; (void)ws_size;
    const float* x  = (const float*)d_in[0];
    const float* W1 = (const float*)d_in[1];
    const float* b1 = (const float*)d_in[2];
    const float* W2 = (const float*)d_in[3];
    const float* b2 = (const float*)d_in[4];
    const float* Wq = (const float*)d_in[5];
    const float* bq = (const float*)d_in[6];
    const float* Wk = (const float*)d_in[7];
    const float* bk = (const float*)d_in[8];
    float* out = (float*)d_out;

    char* p = (char*)d_ws;
    float* c1     = (float*)p;            p += (size_t)64 * LL * 4;
    float* feat   = (float*)p;            p += (size_t)64 * LL * 4;
    float* qq     = (float*)p;            p += (size_t)32 * LL * 4;
    float* kk     = (float*)p;            p += (size_t)32 * LL * 4;
    float* qn_f32 = (float*)p;            p += (size_t)LL * D9 * 4;
    float* kn_f32 = (float*)p;            p += (size_t)LL * D9 * 4;
    unsigned short* qn_bf = (unsigned short*)p;  p += (size_t)LL * D9 * 2;
    unsigned short* kn_bf = (unsigned short*)p;  p += (size_t)LL * D9 * 2;
    float* valsS  = (float*)p;            p += (size_t)KSPLIT * NK * LL * 4;
    int*   idxsS  = (int*)p;              p += (size_t)KSPLIT * NK * LL * 4;
    float* vals   = (float*)p;            p += (size_t)TOPK * LL * 4;
    int*   idxs   = (int*)p;              p += (size_t)TOPK * LL * 4;

    convqk_kernel<<<dim3(36, 8), 256, 0, stream>>>(x, Wq, bq, Wk, bk, qq, kk);
    unfold_norm_kernel<<<dim3(36, 2), 256, 0, stream>>>(qq, qn_f32, qn_bf, kk, kn_f32, kn_bf);
    topk_mfma_kernel<<<36 * KSPLIT, 256, 0, stream>>>(qn_bf, kn_bf, valsS, idxsS);
    conv3_co8_kernel<<<dim3(36, 8), 256, 0, stream>>>(x,  W1, b1, c1,   64, 1);
    conv3_co8_kernel<<<dim3(36, 8), 256, 0, stream>>>(c1, W2, b2, feat, 64, 1);
    rerank_kernel<<<LL / 32, 256, 0, stream>>>(valsS, idxsS, qn_f32, kn_f32, vals, idxs);
    gather_out_kernel<<<(64 * LL) / 256, 256, 0, stream>>>(x, feat, vals, idxs, out);
}

// Round 4
// 370.968 us; speedup vs baseline: 4.8233x; 1.3900x over previous
//
#include <hip/hip_runtime.h>
#include <math.h>

#define HH 96
#define WW 96
#define LL 9216          // H*W
#define D9 288           // 32 q-channels * 9 taps
#define TOPK 5
#define NK 6             // per-split list length
#define NCAND 8          // fp32 re-rank candidates
#define KSPLIT 32
#define CPQ (KSPLIT * NK)                // 192 candidate entries per query
#define KEYS_PER_SPLIT (LL / KSPLIT)     // 288
#define PASSES (KEYS_PER_SPLIT / 32)     // 9
#define CHUNKS (32 * 36)                 // 16B chunks per 32-key pass
#define KROW 292                         // LDS row stride in bf16 elems (584B)

typedef short short8 __attribute__((ext_vector_type(8)));
typedef float f32x16 __attribute__((ext_vector_type(16)));

__device__ __forceinline__ float  asf(unsigned u) { union { unsigned u; float f; } a; a.u = u; return a.f; }
__device__ __forceinline__ unsigned asu(float f)  { union { float f; unsigned u; } a; a.f = f; return a.u; }

__device__ __forceinline__ unsigned short f2bf(float f) {
    unsigned u = asu(f);
    unsigned r = u + 0x7fff + ((u >> 16) & 1);   // RNE
    return (unsigned short)(r >> 16);
}

// branch-free insert into descending-sorted array of packed (score|key) floats
template<int N>
__device__ __forceinline__ void ins_packed(float (&v)[N], float x) {
    #pragma unroll
    for (int s = 0; s < N; ++s) {
        float hi = fmaxf(v[s], x);
        x = fminf(v[s], x);
        v[s] = hi;
    }
}

__device__ __forceinline__ bool better_tb(float av, int ai, float bv, int bi) {
    return (av > bv) || (av == bv && ai < bi);
}

template<int N>
__device__ __forceinline__ void insert_tb(float (&v)[N], int (&ix)[N], float nv, int ni) {
    if (better_tb(nv, ni, v[N-1], ix[N-1])) {
        v[N-1] = nv; ix[N-1] = ni;
        #pragma unroll
        for (int s = N-1; s > 0; --s) {
            if (better_tb(v[s], ix[s], v[s-1], ix[s-1])) {
                float tv = v[s]; v[s] = v[s-1]; v[s-1] = tv;
                int ti = ix[s]; ix[s] = ix[s-1]; ix[s-1] = ti;
            }
        }
    }
}

// ---------------- stage 1: conv1 (8 co/block) fused with q/k conv (4+4 co/block) ----------------
__global__ __launch_bounds__(256) void conv_stage1_kernel(
    const float* __restrict__ x,
    const float* __restrict__ W1, const float* __restrict__ b1, float* __restrict__ c1,
    const float* __restrict__ Wq, const float* __restrict__ bq,
    const float* __restrict__ Wk, const float* __restrict__ bk,
    float* __restrict__ qq, float* __restrict__ kk)
{
    int pix = blockIdx.x * 256 + threadIdx.x;   // 36*256 == 9216
    int y = pix / WW, x0 = pix % WW;

    int  offs[9]; bool msk[9];
    #pragma unroll
    for (int u = 0; u < 3; ++u)
        #pragma unroll
        for (int v = 0; v < 3; ++v) {
            int yy = y + u - 1, xx = x0 + v - 1;
            bool ok = ((unsigned)yy < 96u) && ((unsigned)xx < 96u);
            msk[u*3+v]  = ok;
            offs[u*3+v] = ok ? (yy*96 + xx) : 0;
        }

    int g = blockIdx.y;
    if (g < 8) {
        int co0 = g * 8;
        float acc[8];
        #pragma unroll
        for (int j = 0; j < 8; ++j) acc[j] = b1[co0 + j];
        #pragma unroll 2
        for (int ci = 0; ci < 64; ++ci) {
            const float* xp = x + (size_t)ci * LL;
            float v9[9];
            #pragma unroll
            for (int t = 0; t < 9; ++t) v9[t] = msk[t] ? xp[offs[t]] : 0.0f;
            const float* wb = W1 + (size_t)co0 * 64 * 9 + ci * 9;
            #pragma unroll
            for (int j = 0; j < 8; ++j) {
                const float* wp = wb + (size_t)j * 64 * 9;
                #pragma unroll
                for (int t = 0; t < 9; ++t) acc[j] = fmaf(v9[t], wp[t], acc[j]);
            }
        }
        #pragma unroll
        for (int j = 0; j < 8; ++j)
            c1[(size_t)(co0 + j) * LL + pix] = fmaxf(acc[j], 0.0f);
    } else {
        int co0 = (g - 8) * 4;
        float aq[4], ak[4];
        #pragma unroll
        for (int j = 0; j < 4; ++j) { aq[j] = bq[co0 + j]; ak[j] = bk[co0 + j]; }
        #pragma unroll 2
        for (int ci = 0; ci < 64; ++ci) {
            const float* xp = x + (size_t)ci * LL;
            float v9[9];
            #pragma unroll
            for (int t = 0; t < 9; ++t) v9[t] = msk[t] ? xp[offs[t]] : 0.0f;
            #pragma unroll
            for (int j = 0; j < 4; ++j) {
                const float* wpq = Wq + ((size_t)(co0 + j) * 64 + ci) * 9;
                const float* wpk = Wk + ((size_t)(co0 + j) * 64 + ci) * 9;
                #pragma unroll
                for (int t = 0; t < 9; ++t) {
                    aq[j] = fmaf(v9[t], wpq[t], aq[j]);
                    ak[j] = fmaf(v9[t], wpk[t], ak[j]);
                }
            }
        }
        #pragma unroll
        for (int j = 0; j < 4; ++j) {
            qq[(size_t)(co0 + j) * LL + pix] = aq[j];
            kk[(size_t)(co0 + j) * LL + pix] = ak[j];
        }
    }
}

// ---------------- conv2: direct 3x3, 8 output channels per block ----------------
__global__ __launch_bounds__(256) void conv3_co8_kernel(
    const float* __restrict__ in, const float* __restrict__ Wt,
    const float* __restrict__ bias, float* __restrict__ out)
{
    int co0 = blockIdx.y * 8;
    int pix = blockIdx.x * 256 + threadIdx.x;
    int y = pix / WW, x = pix % WW;

    int  offs[9]; bool msk[9];
    #pragma unroll
    for (int u = 0; u < 3; ++u)
        #pragma unroll
        for (int v = 0; v < 3; ++v) {
            int yy = y + u - 1, xx = x + v - 1;
            bool ok = ((unsigned)yy < 96u) && ((unsigned)xx < 96u);
            msk[u*3+v]  = ok;
            offs[u*3+v] = ok ? (yy*96 + xx) : 0;
        }

    float acc[8];
    #pragma unroll
    for (int j = 0; j < 8; ++j) acc[j] = bias[co0 + j];

    #pragma unroll 2
    for (int ci = 0; ci < 64; ++ci) {
        const float* xp = in + (size_t)ci * LL;
        float v9[9];
        #pragma unroll
        for (int t = 0; t < 9; ++t) v9[t] = msk[t] ? xp[offs[t]] : 0.0f;
        const float* wb = Wt + (size_t)co0 * 64 * 9 + ci * 9;
        #pragma unroll
        for (int j = 0; j < 8; ++j) {
            const float* wp = wb + (size_t)j * 64 * 9;
            #pragma unroll
            for (int t = 0; t < 9; ++t) acc[j] = fmaf(v9[t], wp[t], acc[j]);
        }
    }
    #pragma unroll
    for (int j = 0; j < 8; ++j)
        out[(size_t)(co0 + j) * LL + pix] = fmaxf(acc[j], 0.0f);
}

// ------ unfold3 + L2-normalize; [L][288] fp32 + bf16, coalesced, 32 px/block ------
__global__ __launch_bounds__(256) void unfold_norm_kernel(
    const float* __restrict__ qq, float* __restrict__ q_f32, unsigned short* __restrict__ q_bf,
    const float* __restrict__ kk, float* __restrict__ k_f32, unsigned short* __restrict__ k_bf)
{
    const float* in; float* o32; unsigned short* obf;
    if (blockIdx.y == 0) { in = qq; o32 = q_f32; obf = q_bf; }
    else                 { in = kk; o32 = k_f32; obf = k_bf; }

    __shared__ float inv_s[32];
    int tid = threadIdx.x;
    int l0 = blockIdx.x * 32;

    // phase 1: 8 threads per pixel compute inverse norm
    {
        int pxl = tid >> 3, sub = tid & 7;
        int l = l0 + pxl;
        int y = l / WW, xx0 = l % WW;
        float ss = 0.0f;
        #pragma unroll
        for (int cc = 0; cc < 4; ++cc) {
            const float* xp = in + (size_t)(sub * 4 + cc) * LL;
            #pragma unroll
            for (int u = 0; u < 3; ++u) {
                int yy = y + u - 1;
                bool yok = (unsigned)yy < 96u;
                #pragma unroll
                for (int v = 0; v < 3; ++v) {
                    int xv = xx0 + v - 1;
                    float val = (yok && (unsigned)xv < 96u) ? xp[yy*96+xv] : 0.0f;
                    ss = fmaf(val, val, ss);
                }
            }
        }
        ss += __shfl_xor(ss, 1);
        ss += __shfl_xor(ss, 2);
        ss += __shfl_xor(ss, 4);
        if (sub == 0) inv_s[pxl] = 1.0f / fmaxf(sqrtf(ss), 1e-12f);
    }
    __syncthreads();

    // phase 2: 32 px * 72 float4-chunks = 2304, 9 iters, coalesced stores
    #pragma unroll 1
    for (int it = 0; it < 9; ++it) {
        int e = it * 256 + tid;
        int pxl = e / 72, dc = e - pxl * 72;
        int l = l0 + pxl;
        int y = l / WW, xx0 = l % WW;
        float inv = inv_s[pxl];
        float4 o; float* op = &o.x;
        #pragma unroll
        for (int i = 0; i < 4; ++i) {
            int d = dc * 4 + i;
            int c = d / 9, rm = d - c * 9;
            int u = rm / 3, v = rm - u * 3;
            int yy = y + u - 1, xv = xx0 + v - 1;
            op[i] = ((unsigned)yy < 96u && (unsigned)xv < 96u)
                    ? in[(size_t)c * LL + yy*96 + xv] * inv : 0.0f;
        }
        *(float4*)(o32 + (size_t)l * D9 + dc * 4) = o;
        unsigned short b4[4];
        #pragma unroll
        for (int i = 0; i < 4; ++i) b4[i] = f2bf(op[i]);
        *(uint2*)(obf + (size_t)l * D9 + dc * 4) = *(uint2*)b4;
    }
}

// ---------------- MFMA similarity + packed streaming top-6 per key-split ----------------
// Output layout: query-major [q][split*NK + s] (coalesced read in rerank).
__global__ __launch_bounds__(256, 2) void topk_mfma_kernel(
    const unsigned short* __restrict__ qn_bf, const unsigned short* __restrict__ kn_bf,
    float* __restrict__ valsQ, int* __restrict__ idxsQ)
{
    __shared__ unsigned short ks[2][32 * KROW];

    int tid  = threadIdx.x;
    int lane = tid & 63;
    int col = lane & 31, khalf = lane >> 5;
    int qtile = blockIdx.x >> 5;
    int split = blockIdx.x & 31;
    int q0w = qtile * 256 + (tid >> 6) * 64;
    int key0 = split * KEYS_PER_SPLIT;

    short8 qf[2][18];
    #pragma unroll
    for (int b = 0; b < 2; ++b) {
        const unsigned short* qrow = qn_bf + (size_t)(q0w + b*32 + col) * D9 + khalf * 8;
        #pragma unroll
        for (int dg = 0; dg < 18; ++dg)
            qf[b][dg] = *(const short8*)(qrow + dg * 16);
    }

    float lv0[NK], lv1[NK];
    #pragma unroll
    for (int s = 0; s < NK; ++s) { lv0[s] = -INFINITY; lv1[s] = -INFINITY; }

    const char* kg = (const char*)kn_bf;
    uint4 pre[5];

    #pragma unroll
    for (int c0 = 0; c0 < 5; ++c0) {
        int c = tid + c0 * 256;
        if (c < CHUNKS) {
            int key = c / 36, off = c - key * 36;
            pre[c0] = *(const uint4*)(kg + (size_t)(key0 + key) * 576 + off * 16);
        }
    }
    #pragma unroll
    for (int c0 = 0; c0 < 5; ++c0) {
        int c = tid + c0 * 256;
        if (c < CHUNKS) {
            int key = c / 36, off = c - key * 36;
            char* d = (char*)ks[0] + key * (KROW*2) + off * 16;
            *(uint2*)d       = *(uint2*)&pre[c0];
            *(uint2*)(d + 8) = *((uint2*)&pre[c0] + 1);
        }
    }
    __syncthreads();

    for (int p = 0; p < PASSES; ++p) {
        if (p + 1 < PASSES) {
            #pragma unroll
            for (int c0 = 0; c0 < 5; ++c0) {
                int c = tid + c0 * 256;
                if (c < CHUNKS) {
                    int key = c / 36, off = c - key * 36;
                    pre[c0] = *(const uint4*)(kg + (size_t)(key0 + (p+1)*32 + key) * 576 + off * 16);
                }
            }
        }

        f32x16 acc0 = {}, acc1 = {};
        const char* kb = (const char*)ks[p & 1] + (size_t)col * (KROW*2) + khalf * 16;
        #pragma unroll
        for (int dg = 0; dg < 18; ++dg) {
            short8 af;
            *(uint2*)&af       = *(const uint2*)(kb + dg * 32);
            *((uint2*)&af + 1) = *(const uint2*)(kb + dg * 32 + 8);
            acc0 = __builtin_amdgcn_mfma_f32_32x32x16_bf16(af, qf[0][dg], acc0, 0, 0, 0);
            acc1 = __builtin_amdgcn_mfma_f32_32x32x16_bf16(af, qf[1][dg], acc1, 0, 0, 0);
        }

        int lbase = p * 32 + 4 * khalf;
        #pragma unroll
        for (int r = 0; r < 16; ++r) {
            unsigned lkey = (unsigned)(lbase + (r & 3) + 8 * (r >> 2));
            ins_packed<NK>(lv0, asf((asu(acc0[r]) & 0xFFFFFE00u) | lkey));
            ins_packed<NK>(lv1, asf((asu(acc1[r]) & 0xFFFFFE00u) | lkey));
        }

        if (p + 1 < PASSES) {
            #pragma unroll
            for (int c0 = 0; c0 < 5; ++c0) {
                int c = tid + c0 * 256;
                if (c < CHUNKS) {
                    int key = c / 36, off = c - key * 36;
                    char* d = (char*)ks[(p+1) & 1] + key * (KROW*2) + off * 16;
                    *(uint2*)d       = *(uint2*)&pre[c0];
                    *(uint2*)(d + 8) = *((uint2*)&pre[c0] + 1);
                }
            }
        }
        __syncthreads();
    }

    #pragma unroll
    for (int b = 0; b < 2; ++b) {
        float* lv = b ? lv1 : lv0;
        float pv[NK];
        #pragma unroll
        for (int s = 0; s < NK; ++s) pv[s] = __shfl_xor(lv[s], 32);
        #pragma unroll
        for (int s = 0; s < NK; ++s) {
            float x = pv[s];
            #pragma unroll
            for (int t = 0; t < NK; ++t) {
                float hi = fmaxf(lv[t], x);
                x = fminf(lv[t], x);
                lv[t] = hi;
            }
        }
        if (lane < 32) {
            int q = q0w + b * 32 + col;
            float* vq = valsQ + (size_t)q * CPQ + split * NK;
            int*   iq = idxsQ + (size_t)q * CPQ + split * NK;
            #pragma unroll
            for (int s = 0; s < NK; ++s) {
                unsigned u = asu(lv[s]);
                vq[s] = asf(u & 0xFFFFFE00u);
                iq[s] = key0 + (int)(u & 0x1FFu);
            }
        }
    }
}

// -------- 32 lanes/query: parallel merge -> top-8 candidates -> exact fp32 re-rank --------
__global__ __launch_bounds__(256) void rerank_kernel(
    const float* __restrict__ valsQ, const int* __restrict__ idxsQ,
    const float* __restrict__ qn_f32, const float* __restrict__ kn_f32,
    float* __restrict__ vals, int* __restrict__ idxs)
{
    int tid = threadIdx.x;
    int lane = tid & 63;
    int half = lane >> 5, l32 = lane & 31;
    int q = blockIdx.x * 8 + (tid >> 6) * 2 + half;

    // lane l32 owns split l32's sorted-descending 6 entries (coalesced reads)
    const float* vq = valsQ + (size_t)q * CPQ + l32 * NK;
    const int*   iq = idxsQ + (size_t)q * CPQ + l32 * NK;
    float v[NK]; int ii[NK];
    #pragma unroll
    for (int s = 0; s < NK; ++s) { v[s] = vq[s]; ii[s] = iq[s]; }

    // 8 rounds of wave-parallel argmax over the 32 list heads
    int ckey[NCAND];
    #pragma unroll
    for (int it = 0; it < NCAND; ++it) {
        float cv = v[0];
        int ca = (ii[0] << 5) | l32;              // (key, lane) for deterministic ties
        #pragma unroll
        for (int st = 1; st < 32; st <<= 1) {
            float ov = __shfl_xor(cv, st);
            int oa = __shfl_xor(ca, st);
            if (ov > cv || (ov == cv && oa < ca)) { cv = ov; ca = oa; }
        }
        ckey[it] = ca >> 5;
        if ((ca & 31) == l32) {                   // winner pops its head
            #pragma unroll
            for (int s = 0; s < NK-1; ++s) { v[s] = v[s+1]; ii[s] = ii[s+1]; }
            v[NK-1] = -INFINITY;
        }
    }

    // exact fp32 dot: 4 lanes per candidate
    int r = l32 >> 2, part = l32 & 3;
    const float4* qr = (const float4*)(qn_f32 + (size_t)q * D9) + part * 18;
    const float4* kr = (const float4*)(kn_f32 + (size_t)ckey[r] * D9) + part * 18;
    float s0 = 0.f, s1 = 0.f, s2 = 0.f, s3 = 0.f;
    #pragma unroll
    for (int i2 = 0; i2 < 18; ++i2) {
        float4 a = qr[i2], b = kr[i2];
        s0 = fmaf(a.x, b.x, s0); s1 = fmaf(a.y, b.y, s1);
        s2 = fmaf(a.z, b.z, s2); s3 = fmaf(a.w, b.w, s3);
    }
    float sc = (s0 + s1) + (s2 + s3);
    sc += __shfl_xor(sc, 1);
    sc += __shfl_xor(sc, 2);

    // top-5 with exact scores + lax.top_k tie-break
    float bv[TOPK]; int bi[TOPK];
    #pragma unroll
    for (int s = 0; s < TOPK; ++s) { bv[s] = -INFINITY; bi[s] = 0x7fffffff; }
    #pragma unroll
    for (int cc = 0; cc < NCAND; ++cc) {
        float sv = __shfl(sc, half * 32 + cc * 4);
        insert_tb<TOPK>(bv, bi, sv, ckey[cc]);
    }
    if (l32 == 0) {
        #pragma unroll
        for (int s = 0; s < TOPK; ++s) {
            vals[(size_t)s * LL + q] = bv[s];
            idxs[(size_t)s * LL + q] = bi[s];
        }
    }
}

// ------------- epilogue: gather(top-k idx) -> fold/9 -> *S, sum/4, + feat + x -------------
__global__ __launch_bounds__(256) void gather_out_kernel(
    const float* __restrict__ x, const float* __restrict__ feat,
    const float* __restrict__ vals, const int* __restrict__ idxs,
    float* __restrict__ out)
{
    int t = blockIdx.x * 256 + threadIdx.x;
    int c = t / LL, pix = t - c * LL;
    int y = pix / WW, x0 = pix - y * WW;
    const float* xc = x + (size_t)c * LL;
    float acc = 0.0f;
    #pragma unroll 1
    for (int s = 1; s < TOPK; ++s) {
        float S = vals[(size_t)s * LL + pix];
        float sum = 0.0f;
        #pragma unroll
        for (int i = 0; i < 3; ++i) {
            int qy = y + 1 - i;
            #pragma unroll
            for (int j = 0; j < 3; ++j) {
                int qx = x0 + 1 - j;
                if ((unsigned)qy < 96u && (unsigned)qx < 96u) {
                    int l = idxs[(size_t)s * LL + qy * WW + qx];
                    int yl = l / WW, xl = l - yl * WW;
                    int sy = yl + i - 1, sx = xl + j - 1;
                    if ((unsigned)sy < 96u && (unsigned)sx < 96u)
                        sum += xc[sy * WW + sx];
                }
            }
        }
        acc = fmaf(S, sum * (1.0f/9.0f), acc);
    }
    out[t] = feat[t] + xc[pix] + acc * 0.25f;
}

extern "C" void kernel_launch(void* const* d_in, const int* in_sizes, int n_in,
                              void* d_out, int out_size, void* d_ws, size_t ws_size,
                              hipStream_t stream)
{
    (void)in_sizes; (void)n_in; (void)out_size; (void)ws_size;
    const float* x  = (const float*)d_in[0];
    const float* W1 = (const float*)d_in[1];
    const float* b1 = (const float*)d_in[2];
    const float* W2 = (const float*)d_in[3];
    const float* b2 = (const float*)d_in[4];
    const float* Wq = (const float*)d_in[5];
    const float* bq = (const float*)d_in[6];
    const float* Wk = (const float*)d_in[7];
    const float* bk = (const float*)d_in[8];
    float* out = (float*)d_out;

    char* p = (char*)d_ws;
    float* c1     = (float*)p;            p += (size_t)64 * LL * 4;
    float* feat   = (float*)p;            p += (size_t)64 * LL * 4;
    float* qq     = (float*)p;            p += (size_t)32 * LL * 4;
    float* kk     = (float*)p;            p += (size_t)32 * LL * 4;
    float* qn_f32 = (float*)p;            p += (size_t)LL * D9 * 4;
    float* kn_f32 = (float*)p;            p += (size_t)LL * D9 * 4;
    unsigned short* qn_bf = (unsigned short*)p;  p += (size_t)LL * D9 * 2;
    unsigned short* kn_bf = (unsigned short*)p;  p += (size_t)LL * D9 * 2;
    float* valsQ  = (float*)p;            p += (size_t)LL * CPQ * 4;
    int*   idxsQ  = (int*)p;              p += (size_t)LL * CPQ * 4;
    float* vals   = (float*)p;            p += (size_t)TOPK * LL * 4;
    int*   idxs   = (int*)p;              p += (size_t)TOPK * LL * 4;

    conv_stage1_kernel<<<dim3(36, 16), 256, 0, stream>>>(x, W1, b1, c1, Wq, bq, Wk, bk, qq, kk);
    unfold_norm_kernel<<<dim3(288, 2), 256, 0, stream>>>(qq, qn_f32, qn_bf, kk, kn_f32, kn_bf);
    topk_mfma_kernel<<<36 * KSPLIT, 256, 0, stream>>>(qn_bf, kn_bf, valsQ, idxsQ);
    conv3_co8_kernel<<<dim3(36, 8), 256, 0, stream>>>(c1, W2, b2, feat);
    rerank_kernel<<<LL / 8, 256, 0, stream>>>(valsQ, idxsQ, qn_f32, kn_f32, vals, idxs);
    gather_out_kernel<<<(64 * LL) / 256, 256, 0, stream>>>(x, feat, vals, idxs, out);
}

// Round 5
// 358.300 us; speedup vs baseline: 4.9938x; 1.0354x over previous
//
#include <hip/hip_runtime.h>
#include <math.h>

#define HH 96
#define WW 96
#define LL 9216          // H*W
#define D9 288           // 32 q-channels * 9 taps
#define TOPK 5
#define NK 6             // per-split list length
#define NCAND 8          // fp32 re-rank candidates
#define KSPLIT 32
#define CPQ (KSPLIT * NK)                // 192 packed entries per query
#define KEYS_PER_SPLIT (LL / KSPLIT)     // 288
#define PASSES (KEYS_PER_SPLIT / 32)     // 9
#define CHUNKS (32 * 36)                 // 16B chunks per 32-key pass
#define KROW 292                         // LDS row stride in bf16 elems (584B, 2-way banks)

typedef short short8 __attribute__((ext_vector_type(8)));
typedef float f32x16 __attribute__((ext_vector_type(16)));

__device__ __forceinline__ float  asf(unsigned u) { union { unsigned u; float f; } a; a.u = u; return a.f; }
__device__ __forceinline__ unsigned asu(float f)  { union { float f; unsigned u; } a; a.f = f; return a.u; }

__device__ __forceinline__ unsigned short f2bf(float f) {
    unsigned u = asu(f);
    unsigned r = u + 0x7fff + ((u >> 16) & 1);   // RNE
    return (unsigned short)(r >> 16);
}

// branch-free insert into descending-sorted array of packed (score|key) floats
template<int N>
__device__ __forceinline__ void ins_packed(float (&v)[N], float x) {
    #pragma unroll
    for (int s = 0; s < N; ++s) {
        float hi = fmaxf(v[s], x);
        x = fminf(v[s], x);
        v[s] = hi;
    }
}

__device__ __forceinline__ bool better_tb(float av, int ai, float bv, int bi) {
    return (av > bv) || (av == bv && ai < bi);
}

template<int N>
__device__ __forceinline__ void insert_tb(float (&v)[N], int (&ix)[N], float nv, int ni) {
    if (better_tb(nv, ni, v[N-1], ix[N-1])) {
        v[N-1] = nv; ix[N-1] = ni;
        #pragma unroll
        for (int s = N-1; s > 0; --s) {
            if (better_tb(v[s], ix[s], v[s-1], ix[s-1])) {
                float tv = v[s]; v[s] = v[s-1]; v[s-1] = tv;
                int ti = ix[s]; ix[s] = ix[s-1]; ix[s-1] = ti;
            }
        }
    }
}

// ---------------- stage 1: conv1 (8 co/block) fused with q/k conv (4+4 co/block) ----------------
__global__ __launch_bounds__(256) void conv_stage1_kernel(
    const float* __restrict__ x,
    const float* __restrict__ W1, const float* __restrict__ b1, float* __restrict__ c1,
    const float* __restrict__ Wq, const float* __restrict__ bq,
    const float* __restrict__ Wk, const float* __restrict__ bk,
    float* __restrict__ qq, float* __restrict__ kk)
{
    int pix = blockIdx.x * 256 + threadIdx.x;   // 36*256 == 9216
    int y = pix / WW, x0 = pix % WW;

    int  offs[9]; bool msk[9];
    #pragma unroll
    for (int u = 0; u < 3; ++u)
        #pragma unroll
        for (int v = 0; v < 3; ++v) {
            int yy = y + u - 1, xx = x0 + v - 1;
            bool ok = ((unsigned)yy < 96u) && ((unsigned)xx < 96u);
            msk[u*3+v]  = ok;
            offs[u*3+v] = ok ? (yy*96 + xx) : 0;
        }

    int g = blockIdx.y;
    if (g < 8) {
        int co0 = g * 8;
        float acc[8];
        #pragma unroll
        for (int j = 0; j < 8; ++j) acc[j] = b1[co0 + j];
        #pragma unroll 2
        for (int ci = 0; ci < 64; ++ci) {
            const float* xp = x + (size_t)ci * LL;
            float v9[9];
            #pragma unroll
            for (int t = 0; t < 9; ++t) v9[t] = msk[t] ? xp[offs[t]] : 0.0f;
            const float* wb = W1 + (size_t)co0 * 64 * 9 + ci * 9;
            #pragma unroll
            for (int j = 0; j < 8; ++j) {
                const float* wp = wb + (size_t)j * 64 * 9;
                #pragma unroll
                for (int t = 0; t < 9; ++t) acc[j] = fmaf(v9[t], wp[t], acc[j]);
            }
        }
        #pragma unroll
        for (int j = 0; j < 8; ++j)
            c1[(size_t)(co0 + j) * LL + pix] = fmaxf(acc[j], 0.0f);
    } else {
        int co0 = (g - 8) * 4;
        float aq[4], ak[4];
        #pragma unroll
        for (int j = 0; j < 4; ++j) { aq[j] = bq[co0 + j]; ak[j] = bk[co0 + j]; }
        #pragma unroll 2
        for (int ci = 0; ci < 64; ++ci) {
            const float* xp = x + (size_t)ci * LL;
            float v9[9];
            #pragma unroll
            for (int t = 0; t < 9; ++t) v9[t] = msk[t] ? xp[offs[t]] : 0.0f;
            #pragma unroll
            for (int j = 0; j < 4; ++j) {
                const float* wpq = Wq + ((size_t)(co0 + j) * 64 + ci) * 9;
                const float* wpk = Wk + ((size_t)(co0 + j) * 64 + ci) * 9;
                #pragma unroll
                for (int t = 0; t < 9; ++t) {
                    aq[j] = fmaf(v9[t], wpq[t], aq[j]);
                    ak[j] = fmaf(v9[t], wpk[t], ak[j]);
                }
            }
        }
        #pragma unroll
        for (int j = 0; j < 4; ++j) {
            qq[(size_t)(co0 + j) * LL + pix] = aq[j];
            kk[(size_t)(co0 + j) * LL + pix] = ak[j];
        }
    }
}

// ---------------- conv2: direct 3x3, 8 output channels per block ----------------
__global__ __launch_bounds__(256) void conv3_co8_kernel(
    const float* __restrict__ in, const float* __restrict__ Wt,
    const float* __restrict__ bias, float* __restrict__ out)
{
    int co0 = blockIdx.y * 8;
    int pix = blockIdx.x * 256 + threadIdx.x;
    int y = pix / WW, x = pix % WW;

    int  offs[9]; bool msk[9];
    #pragma unroll
    for (int u = 0; u < 3; ++u)
        #pragma unroll
        for (int v = 0; v < 3; ++v) {
            int yy = y + u - 1, xx = x + v - 1;
            bool ok = ((unsigned)yy < 96u) && ((unsigned)xx < 96u);
            msk[u*3+v]  = ok;
            offs[u*3+v] = ok ? (yy*96 + xx) : 0;
        }

    float acc[8];
    #pragma unroll
    for (int j = 0; j < 8; ++j) acc[j] = bias[co0 + j];

    #pragma unroll 2
    for (int ci = 0; ci < 64; ++ci) {
        const float* xp = in + (size_t)ci * LL;
        float v9[9];
        #pragma unroll
        for (int t = 0; t < 9; ++t) v9[t] = msk[t] ? xp[offs[t]] : 0.0f;
        const float* wb = Wt + (size_t)co0 * 64 * 9 + ci * 9;
        #pragma unroll
        for (int j = 0; j < 8; ++j) {
            const float* wp = wb + (size_t)j * 64 * 9;
            #pragma unroll
            for (int t = 0; t < 9; ++t) acc[j] = fmaf(v9[t], wp[t], acc[j]);
        }
    }
    #pragma unroll
    for (int j = 0; j < 8; ++j)
        out[(size_t)(co0 + j) * LL + pix] = fmaxf(acc[j], 0.0f);
}

// ---------------- transpose x: [64][LL] -> xT [LL][64] (for coalesced gather) ----------------
__global__ __launch_bounds__(256) void transpose_x_kernel(
    const float* __restrict__ x, float* __restrict__ xT)
{
    __shared__ float t[64][65];
    int pix0 = blockIdx.x * 64;
    int lp = threadIdx.x & 63, cg = threadIdx.x >> 6;
    #pragma unroll
    for (int cc = 0; cc < 16; ++cc) {
        int c = cg * 16 + cc;
        t[c][lp] = x[(size_t)c * LL + pix0 + lp];
    }
    __syncthreads();
    #pragma unroll
    for (int pp = 0; pp < 16; ++pp) {
        int pl = cg * 16 + pp;
        xT[(size_t)(pix0 + pl) * 64 + lp] = t[lp][pl];
    }
}

// ------ unfold3 + L2-normalize; [L][288] fp32 + bf16, coalesced, 32 px/block ------
__global__ __launch_bounds__(256) void unfold_norm_kernel(
    const float* __restrict__ qq, float* __restrict__ q_f32, unsigned short* __restrict__ q_bf,
    const float* __restrict__ kk, float* __restrict__ k_f32, unsigned short* __restrict__ k_bf)
{
    const float* in; float* o32; unsigned short* obf;
    if (blockIdx.y == 0) { in = qq; o32 = q_f32; obf = q_bf; }
    else                 { in = kk; o32 = k_f32; obf = k_bf; }

    __shared__ float inv_s[32];
    int tid = threadIdx.x;
    int l0 = blockIdx.x * 32;

    // phase 1: 8 threads per pixel compute inverse norm
    {
        int pxl = tid >> 3, sub = tid & 7;
        int l = l0 + pxl;
        int y = l / WW, xx0 = l % WW;
        float ss = 0.0f;
        #pragma unroll
        for (int cc = 0; cc < 4; ++cc) {
            const float* xp = in + (size_t)(sub * 4 + cc) * LL;
            #pragma unroll
            for (int u = 0; u < 3; ++u) {
                int yy = y + u - 1;
                bool yok = (unsigned)yy < 96u;
                #pragma unroll
                for (int v = 0; v < 3; ++v) {
                    int xv = xx0 + v - 1;
                    float val = (yok && (unsigned)xv < 96u) ? xp[yy*96+xv] : 0.0f;
                    ss = fmaf(val, val, ss);
                }
            }
        }
        ss += __shfl_xor(ss, 1);
        ss += __shfl_xor(ss, 2);
        ss += __shfl_xor(ss, 4);
        if (sub == 0) inv_s[pxl] = 1.0f / fmaxf(sqrtf(ss), 1e-12f);
    }
    __syncthreads();

    // phase 2: 32 px * 72 float4-chunks = 2304, 9 iters, coalesced stores
    #pragma unroll 1
    for (int it = 0; it < 9; ++it) {
        int e = it * 256 + tid;
        int pxl = e / 72, dc = e - pxl * 72;
        int l = l0 + pxl;
        int y = l / WW, xx0 = l % WW;
        float inv = inv_s[pxl];
        float4 o; float* op = &o.x;
        #pragma unroll
        for (int i = 0; i < 4; ++i) {
            int d = dc * 4 + i;
            int c = d / 9, rm = d - c * 9;
            int u = rm / 3, v = rm - u * 3;
            int yy = y + u - 1, xv = xx0 + v - 1;
            op[i] = ((unsigned)yy < 96u && (unsigned)xv < 96u)
                    ? in[(size_t)c * LL + yy*96 + xv] * inv : 0.0f;
        }
        *(float4*)(o32 + (size_t)l * D9 + dc * 4) = o;
        unsigned short b4[4];
        #pragma unroll
        for (int i = 0; i < 4; ++i) b4[i] = f2bf(op[i]);
        *(uint2*)(obf + (size_t)l * D9 + dc * 4) = *(uint2*)b4;
    }
}

// ---------------- MFMA similarity + guarded packed top-6 per key-split ----------------
// Output: query-major packed floats [q][split*NK + s]; key = split*288 + (bits & 0x1FF).
__global__ __launch_bounds__(256, 2) void topk_mfma_kernel(
    const unsigned short* __restrict__ qn_bf, const unsigned short* __restrict__ kn_bf,
    float* __restrict__ valsQ)
{
    __shared__ unsigned short ks[2][32 * KROW];

    int tid  = threadIdx.x;
    int lane = tid & 63;
    int col = lane & 31, khalf = lane >> 5;
    int qtile = blockIdx.x >> 5;
    int split = blockIdx.x & 31;
    int q0w = qtile * 256 + (tid >> 6) * 64;
    int key0 = split * KEYS_PER_SPLIT;

    short8 qf[2][18];
    #pragma unroll
    for (int b = 0; b < 2; ++b) {
        const unsigned short* qrow = qn_bf + (size_t)(q0w + b*32 + col) * D9 + khalf * 8;
        #pragma unroll
        for (int dg = 0; dg < 18; ++dg)
            qf[b][dg] = *(const short8*)(qrow + dg * 16);
    }

    float lv0[NK], lv1[NK];
    #pragma unroll
    for (int s = 0; s < NK; ++s) { lv0[s] = -INFINITY; lv1[s] = -INFINITY; }

    const char* kg = (const char*)kn_bf;
    uint4 pre[5];

    #pragma unroll
    for (int c0 = 0; c0 < 5; ++c0) {
        int c = tid + c0 * 256;
        if (c < CHUNKS) {
            int key = c / 36, off = c - key * 36;
            pre[c0] = *(const uint4*)(kg + (size_t)(key0 + key) * 576 + off * 16);
        }
    }
    #pragma unroll
    for (int c0 = 0; c0 < 5; ++c0) {
        int c = tid + c0 * 256;
        if (c < CHUNKS) {
            int key = c / 36, off = c - key * 36;
            char* d = (char*)ks[0] + key * (KROW*2) + off * 16;
            *(uint2*)d       = *(uint2*)&pre[c0];
            *(uint2*)(d + 8) = *((uint2*)&pre[c0] + 1);
        }
    }
    __syncthreads();

    for (int p = 0; p < PASSES; ++p) {
        if (p + 1 < PASSES) {
            #pragma unroll
            for (int c0 = 0; c0 < 5; ++c0) {
                int c = tid + c0 * 256;
                if (c < CHUNKS) {
                    int key = c / 36, off = c - key * 36;
                    pre[c0] = *(const uint4*)(kg + (size_t)(key0 + (p+1)*32 + key) * 576 + off * 16);
                }
            }
        }

        f32x16 acc0 = {}, acc1 = {};
        const char* kb = (const char*)ks[p & 1] + (size_t)col * (KROW*2) + khalf * 16;
        #pragma unroll
        for (int dg = 0; dg < 18; ++dg) {
            short8 af;
            *(uint2*)&af       = *(const uint2*)(kb + dg * 32);
            *((uint2*)&af + 1) = *(const uint2*)(kb + dg * 32 + 8);
            acc0 = __builtin_amdgcn_mfma_f32_32x32x16_bf16(af, qf[0][dg], acc0, 0, 0, 0);
            acc1 = __builtin_amdgcn_mfma_f32_32x32x16_bf16(af, qf[1][dg], acc1, 0, 0, 0);
        }

        // guarded packed insert: most scores fail the head test -> skipped body
        int lbase = p * 32 + 4 * khalf;
        #pragma unroll
        for (int r = 0; r < 16; ++r) {
            unsigned lkey = (unsigned)(lbase + (r & 3) + 8 * (r >> 2));
            float p0 = asf((asu(acc0[r]) & 0xFFFFFE00u) | lkey);
            if (p0 > lv0[NK-1]) ins_packed<NK>(lv0, p0);
            float p1 = asf((asu(acc1[r]) & 0xFFFFFE00u) | lkey);
            if (p1 > lv1[NK-1]) ins_packed<NK>(lv1, p1);
        }

        if (p + 1 < PASSES) {
            #pragma unroll
            for (int c0 = 0; c0 < 5; ++c0) {
                int c = tid + c0 * 256;
                if (c < CHUNKS) {
                    int key = c / 36, off = c - key * 36;
                    char* d = (char*)ks[(p+1) & 1] + key * (KROW*2) + off * 16;
                    *(uint2*)d       = *(uint2*)&pre[c0];
                    *(uint2*)(d + 8) = *((uint2*)&pre[c0] + 1);
                }
            }
        }
        __syncthreads();
    }

    // merge lane pair (lane, lane^32): same query, disjoint keys; write packed
    #pragma unroll
    for (int b = 0; b < 2; ++b) {
        float* lv = b ? lv1 : lv0;
        float pv[NK];
        #pragma unroll
        for (int s = 0; s < NK; ++s) pv[s] = __shfl_xor(lv[s], 32);
        #pragma unroll
        for (int s = 0; s < NK; ++s) {
            float x = pv[s];
            #pragma unroll
            for (int t = 0; t < NK; ++t) {
                float hi = fmaxf(lv[t], x);
                x = fminf(lv[t], x);
                lv[t] = hi;
            }
        }
        if (lane < 32) {
            int q = q0w + b * 32 + col;
            float* vq = valsQ + (size_t)q * CPQ + split * NK;
            #pragma unroll
            for (int s = 0; s < NK; ++s) vq[s] = lv[s];
        }
    }
}

// -------- 32 lanes/query: packed merge -> top-8 candidates -> exact fp32 re-rank --------
__global__ __launch_bounds__(256) void rerank_kernel(
    const float* __restrict__ valsQ,
    const float* __restrict__ qn_f32, const float* __restrict__ kn_f32,
    float* __restrict__ vals, int* __restrict__ idxs)
{
    int tid = threadIdx.x;
    int lane = tid & 63;
    int half = lane >> 5, l32 = lane & 31;
    int q = blockIdx.x * 8 + (tid >> 6) * 2 + half;

    // lane l32 owns split l32's sorted-descending packed entries
    const float* vq = valsQ + (size_t)q * CPQ + l32 * NK;
    float v[NK];
    #pragma unroll
    for (int s = 0; s < NK; ++s) v[s] = vq[s];

    // 8 rounds of wave-parallel argmax over the 32 list heads
    int ckey[NCAND];
    #pragma unroll
    for (int it = 0; it < NCAND; ++it) {
        float cv = v[0];
        int cl = l32;
        #pragma unroll
        for (int st = 1; st < 32; st <<= 1) {
            float ov = __shfl_xor(cv, st);
            int ol = __shfl_xor(cl, st);
            if (ov > cv || (ov == cv && ol < cl)) { cv = ov; cl = ol; }
        }
        ckey[it] = cl * KEYS_PER_SPLIT + (int)(asu(cv) & 0x1FFu);
        if (cl == l32) {                          // winner pops its head
            #pragma unroll
            for (int s = 0; s < NK-1; ++s) v[s] = v[s+1];
            v[NK-1] = -INFINITY;
        }
    }

    // exact fp32 dot: 4 lanes per candidate
    int r = l32 >> 2, part = l32 & 3;
    const float4* qr = (const float4*)(qn_f32 + (size_t)q * D9) + part * 18;
    const float4* kr = (const float4*)(kn_f32 + (size_t)ckey[r] * D9) + part * 18;
    float s0 = 0.f, s1 = 0.f, s2 = 0.f, s3 = 0.f;
    #pragma unroll
    for (int i2 = 0; i2 < 18; ++i2) {
        float4 a = qr[i2], b = kr[i2];
        s0 = fmaf(a.x, b.x, s0); s1 = fmaf(a.y, b.y, s1);
        s2 = fmaf(a.z, b.z, s2); s3 = fmaf(a.w, b.w, s3);
    }
    float sc = (s0 + s1) + (s2 + s3);
    sc += __shfl_xor(sc, 1);
    sc += __shfl_xor(sc, 2);

    // top-5 with exact scores + lax.top_k tie-break
    float bv[TOPK]; int bi[TOPK];
    #pragma unroll
    for (int s = 0; s < TOPK; ++s) { bv[s] = -INFINITY; bi[s] = 0x7fffffff; }
    #pragma unroll
    for (int cc = 0; cc < NCAND; ++cc) {
        float sv = __shfl(sc, half * 32 + cc * 4);
        insert_tb<TOPK>(bv, bi, sv, ckey[cc]);
    }
    if (l32 == 0) {
        #pragma unroll
        for (int s = 0; s < TOPK; ++s) {
            vals[(size_t)s * LL + q] = bv[s];
            idxs[(size_t)s * LL + q] = bi[s];
        }
    }
}

// ------------- epilogue: wave-per-pixel, lanes over channels, coalesced gathers -------------
__global__ __launch_bounds__(256) void gather_out_kernel(
    const float* __restrict__ xT, const float* __restrict__ feat,
    const float* __restrict__ vals, const int* __restrict__ idxs,
    float* __restrict__ out)
{
    int wave = threadIdx.x >> 6, lane = threadIdx.x & 63;
    int pix = blockIdx.x * 4 + wave;
    int y = pix / WW, x0 = pix - y * WW;
    float acc = 0.0f;
    #pragma unroll 1
    for (int s = 1; s < TOPK; ++s) {
        float S = vals[(size_t)s * LL + pix] * (1.0f/9.0f);
        #pragma unroll
        for (int i = 0; i < 3; ++i) {
            int qy = y + 1 - i;
            #pragma unroll
            for (int j = 0; j < 3; ++j) {
                int qx = x0 + 1 - j;
                if ((unsigned)qy < 96u && (unsigned)qx < 96u) {   // wave-uniform
                    int l = idxs[(size_t)s * LL + qy * WW + qx];  // broadcast
                    int yl = l / WW, xl = l - yl * WW;
                    int sy = yl + i - 1, sx = xl + j - 1;
                    if ((unsigned)sy < 96u && (unsigned)sx < 96u) // wave-uniform
                        acc = fmaf(S, xT[(size_t)(sy * WW + sx) * 64 + lane], acc);
                }
            }
        }
    }
    out[(size_t)lane * LL + pix] = feat[(size_t)lane * LL + pix]
                                 + xT[(size_t)pix * 64 + lane] + acc * 0.25f;
}

extern "C" void kernel_launch(void* const* d_in, const int* in_sizes, int n_in,
                              void* d_out, int out_size, void* d_ws, size_t ws_size,
                              hipStream_t stream)
{
    (void)in_sizes; (void)n_in; (void)out_size; (void)ws_size;
    const float* x  = (const float*)d_in[0];
    const float* W1 = (const float*)d_in[1];
    const float* b1 = (const float*)d_in[2];
    const float* W2 = (const float*)d_in[3];
    const float* b2 = (const float*)d_in[4];
    const float* Wq = (const float*)d_in[5];
    const float* bq = (const float*)d_in[6];
    const float* Wk = (const float*)d_in[7];
    const float* bk = (const float*)d_in[8];
    float* out = (float*)d_out;

    char* p = (char*)d_ws;
    float* c1     = (float*)p;            p += (size_t)64 * LL * 4;
    float* feat   = (float*)p;            p += (size_t)64 * LL * 4;
    float* xT     = (float*)p;            p += (size_t)64 * LL * 4;
    float* qq     = (float*)p;            p += (size_t)32 * LL * 4;
    float* kk     = (float*)p;            p += (size_t)32 * LL * 4;
    float* qn_f32 = (float*)p;            p += (size_t)LL * D9 * 4;
    float* kn_f32 = (float*)p;            p += (size_t)LL * D9 * 4;
    unsigned short* qn_bf = (unsigned short*)p;  p += (size_t)LL * D9 * 2;
    unsigned short* kn_bf = (unsigned short*)p;  p += (size_t)LL * D9 * 2;
    float* valsQ  = (float*)p;            p += (size_t)LL * CPQ * 4;
    float* vals   = (float*)p;            p += (size_t)TOPK * LL * 4;
    int*   idxs   = (int*)p;              p += (size_t)TOPK * LL * 4;

    conv_stage1_kernel<<<dim3(36, 16), 256, 0, stream>>>(x, W1, b1, c1, Wq, bq, Wk, bk, qq, kk);
    unfold_norm_kernel<<<dim3(288, 2), 256, 0, stream>>>(qq, qn_f32, qn_bf, kk, kn_f32, kn_bf);
    topk_mfma_kernel<<<36 * KSPLIT, 256, 0, stream>>>(qn_bf, kn_bf, valsQ);
    conv3_co8_kernel<<<dim3(36, 8), 256, 0, stream>>>(c1, W2, b2, feat);
    transpose_x_kernel<<<144, 256, 0, stream>>>(x, xT);
    rerank_kernel<<<LL / 8, 256, 0, stream>>>(valsQ, qn_f32, kn_f32, vals, idxs);
    gather_out_kernel<<<LL / 4, 256, 0, stream>>>(xT, feat, vals, idxs, out);
}

// Round 7
// 307.228 us; speedup vs baseline: 5.8239x; 1.1662x over previous
//
#include <hip/hip_runtime.h>
#include <math.h>

#define HH 96
#define WW 96
#define LL 9216          // H*W
#define D9 288           // 32 q-channels * 9 taps
#define TOPK 5
#define NK 6             // per-split list length
#define NCAND 8          // fp32 re-rank candidates
#define KSPLIT 32
#define CPQ (KSPLIT * NK)                // 192 packed entries per query
#define KEYS_PER_SPLIT (LL / KSPLIT)     // 288
#define PASSES (KEYS_PER_SPLIT / 32)     // 9
#define CHUNKS (32 * 36)                 // 16B chunks per 32-key pass
#define KROW 292                         // LDS row stride in bf16 elems (584B, 2-way banks)

typedef short short8 __attribute__((ext_vector_type(8)));
typedef float f32x16 __attribute__((ext_vector_type(16)));

__device__ __forceinline__ float  asf(unsigned u) { union { unsigned u; float f; } a; a.u = u; return a.f; }
__device__ __forceinline__ unsigned asu(float f)  { union { float f; unsigned u; } a; a.f = f; return a.u; }

__device__ __forceinline__ unsigned short f2bf(float f) {
    unsigned u = asu(f);
    unsigned r = u + 0x7fff + ((u >> 16) & 1);   // RNE
    return (unsigned short)(r >> 16);
}

// sorted-desc top-N insert via med3: zero serial depth, N ops.
// v0'=max(v0,x); vi'=med3(v[i-1],v[i],x) -- all from OLD v.
template<int N>
__device__ __forceinline__ void ins_med3(float* v, float x) {
    float nv[N];
    nv[0] = fmaxf(v[0], x);
    #pragma unroll
    for (int s = 1; s < N; ++s) nv[s] = __builtin_amdgcn_fmed3f(v[s-1], v[s], x);
    #pragma unroll
    for (int s = 0; s < N; ++s) v[s] = nv[s];
}

__device__ __forceinline__ bool better_tb(float av, int ai, float bv, int bi) {
    return (av > bv) || (av == bv && ai < bi);
}

template<int N>
__device__ __forceinline__ void insert_tb(float (&v)[N], int (&ix)[N], float nv, int ni) {
    if (better_tb(nv, ni, v[N-1], ix[N-1])) {
        v[N-1] = nv; ix[N-1] = ni;
        #pragma unroll
        for (int s = N-1; s > 0; --s) {
            if (better_tb(v[s], ix[s], v[s-1], ix[s-1])) {
                float tv = v[s]; v[s] = v[s-1]; v[s-1] = tv;
                int ti = ix[s]; ix[s] = ix[s-1]; ix[s-1] = ti;
            }
        }
    }
}

// ---------------- stage 1: conv1 (4 co/block, 16 groups) + q/k conv (4+4, 8 groups) ----------------
__global__ __launch_bounds__(256) void conv_stage1_kernel(
    const float* __restrict__ x,
    const float* __restrict__ W1, const float* __restrict__ b1, float* __restrict__ c1,
    const float* __restrict__ Wq, const float* __restrict__ bq,
    const float* __restrict__ Wk, const float* __restrict__ bk,
    float* __restrict__ qq, float* __restrict__ kk)
{
    int pix = blockIdx.x * 256 + threadIdx.x;   // 36*256 == 9216
    int y = pix / WW, x0 = pix % WW;

    int  offs[9]; bool msk[9];
    #pragma unroll
    for (int u = 0; u < 3; ++u)
        #pragma unroll
        for (int v = 0; v < 3; ++v) {
            int yy = y + u - 1, xx = x0 + v - 1;
            bool ok = ((unsigned)yy < 96u) && ((unsigned)xx < 96u);
            msk[u*3+v]  = ok;
            offs[u*3+v] = ok ? (yy*96 + xx) : 0;
        }

    int g = blockIdx.y;
    if (g < 16) {
        int co0 = g * 4;
        float acc[4];
        #pragma unroll
        for (int j = 0; j < 4; ++j) acc[j] = b1[co0 + j];
        #pragma unroll 2
        for (int ci = 0; ci < 64; ++ci) {
            const float* xp = x + (size_t)ci * LL;
            float v9[9];
            #pragma unroll
            for (int t = 0; t < 9; ++t) v9[t] = msk[t] ? xp[offs[t]] : 0.0f;
            const float* wb = W1 + ((size_t)co0 * 64 + ci) * 9;
            #pragma unroll
            for (int j = 0; j < 4; ++j) {
                const float* wp = wb + (size_t)j * 64 * 9;
                #pragma unroll
                for (int t = 0; t < 9; ++t) acc[j] = fmaf(v9[t], wp[t], acc[j]);
            }
        }
        #pragma unroll
        for (int j = 0; j < 4; ++j)
            c1[(size_t)(co0 + j) * LL + pix] = fmaxf(acc[j], 0.0f);
    } else {
        int co0 = (g - 16) * 4;
        float aq[4], ak[4];
        #pragma unroll
        for (int j = 0; j < 4; ++j) { aq[j] = bq[co0 + j]; ak[j] = bk[co0 + j]; }
        #pragma unroll 2
        for (int ci = 0; ci < 64; ++ci) {
            const float* xp = x + (size_t)ci * LL;
            float v9[9];
            #pragma unroll
            for (int t = 0; t < 9; ++t) v9[t] = msk[t] ? xp[offs[t]] : 0.0f;
            #pragma unroll
            for (int j = 0; j < 4; ++j) {
                const float* wpq = Wq + ((size_t)(co0 + j) * 64 + ci) * 9;
                const float* wpk = Wk + ((size_t)(co0 + j) * 64 + ci) * 9;
                #pragma unroll
                for (int t = 0; t < 9; ++t) {
                    aq[j] = fmaf(v9[t], wpq[t], aq[j]);
                    ak[j] = fmaf(v9[t], wpk[t], ak[j]);
                }
            }
        }
        #pragma unroll
        for (int j = 0; j < 4; ++j) {
            qq[(size_t)(co0 + j) * LL + pix] = aq[j];
            kk[(size_t)(co0 + j) * LL + pix] = ak[j];
        }
    }
}

// ---------------- conv2: direct 3x3, 4 output channels per block (16 groups) ----------------
__global__ __launch_bounds__(256) void conv3_co4_kernel(
    const float* __restrict__ in, const float* __restrict__ Wt,
    const float* __restrict__ bias, float* __restrict__ out)
{
    int co0 = blockIdx.y * 4;
    int pix = blockIdx.x * 256 + threadIdx.x;
    int y = pix / WW, x = pix % WW;

    int  offs[9]; bool msk[9];
    #pragma unroll
    for (int u = 0; u < 3; ++u)
        #pragma unroll
        for (int v = 0; v < 3; ++v) {
            int yy = y + u - 1, xx = x + v - 1;
            bool ok = ((unsigned)yy < 96u) && ((unsigned)xx < 96u);
            msk[u*3+v]  = ok;
            offs[u*3+v] = ok ? (yy*96 + xx) : 0;
        }

    float acc[4];
    #pragma unroll
    for (int j = 0; j < 4; ++j) acc[j] = bias[co0 + j];

    #pragma unroll 2
    for (int ci = 0; ci < 64; ++ci) {
        const float* xp = in + (size_t)ci * LL;
        float v9[9];
        #pragma unroll
        for (int t = 0; t < 9; ++t) v9[t] = msk[t] ? xp[offs[t]] : 0.0f;
        const float* wb = Wt + ((size_t)co0 * 64 + ci) * 9;
        #pragma unroll
        for (int j = 0; j < 4; ++j) {
            const float* wp = wb + (size_t)j * 64 * 9;
            #pragma unroll
            for (int t = 0; t < 9; ++t) acc[j] = fmaf(v9[t], wp[t], acc[j]);
        }
    }
    #pragma unroll
    for (int j = 0; j < 4; ++j)
        out[(size_t)(co0 + j) * LL + pix] = fmaxf(acc[j], 0.0f);
}

// ---------------- transpose x: [64][LL] -> xT [LL][64] (for coalesced gather) ----------------
__global__ __launch_bounds__(256) void transpose_x_kernel(
    const float* __restrict__ x, float* __restrict__ xT)
{
    __shared__ float t[64][65];
    int pix0 = blockIdx.x * 64;
    int lp = threadIdx.x & 63, cg = threadIdx.x >> 6;
    #pragma unroll
    for (int cc = 0; cc < 16; ++cc) {
        int c = cg * 16 + cc;
        t[c][lp] = x[(size_t)c * LL + pix0 + lp];
    }
    __syncthreads();
    #pragma unroll
    for (int pp = 0; pp < 16; ++pp) {
        int pl = cg * 16 + pp;
        xT[(size_t)(pix0 + pl) * 64 + lp] = t[lp][pl];
    }
}

// ------ unfold3 + L2-normalize; LDS-staged tile, [L][288] fp32 + bf16, coalesced ------
// Block = 32 pixels of one image row segment. blockIdx.y: 0=q, 1=k.
__global__ __launch_bounds__(256) void unfold_norm_kernel(
    const float* __restrict__ qq, float* __restrict__ q_f32, unsigned short* __restrict__ q_bf,
    const float* __restrict__ kk, float* __restrict__ k_f32, unsigned short* __restrict__ k_bf)
{
    const float* in; float* o32; unsigned short* obf;
    if (blockIdx.y == 0) { in = qq; o32 = q_f32; obf = q_bf; }
    else                 { in = kk; o32 = k_f32; obf = k_bf; }

    __shared__ float tile[3][32][34];   // [row][chan][col] = 13056 B
    __shared__ float inv_s[32];
    int tid = threadIdx.x;
    int l0 = blockIdx.x * 32;
    int y = l0 / WW, xb = l0 % WW;      // all 32 px share row y

    // stage: 3 rows x 32 ch x 34 cols, coalesced over col
    #pragma unroll
    for (int j = 0; j < 13; ++j) {
        int f = j * 256 + tid;
        if (f < 3 * 32 * 34) {
            int col = f % 34, cc = (f / 34) & 31, r = f / (34 * 32);
            int yy = y + r - 1, xv = xb + col - 1;
            float val = ((unsigned)yy < 96u && (unsigned)xv < 96u)
                        ? in[(size_t)cc * LL + yy * 96 + xv] : 0.0f;
            tile[r][cc][col] = val;
        }
    }
    __syncthreads();

    // phase 1: 8 threads per pixel -> inverse norm
    {
        int pxl = tid >> 3, sub = tid & 7;
        float ss = 0.0f;
        #pragma unroll
        for (int cc = 0; cc < 4; ++cc) {
            int c = sub * 4 + cc;
            #pragma unroll
            for (int u = 0; u < 3; ++u)
                #pragma unroll
                for (int v = 0; v < 3; ++v) {
                    float val = tile[u][c][pxl + v];
                    ss = fmaf(val, val, ss);
                }
        }
        ss += __shfl_xor(ss, 1);
        ss += __shfl_xor(ss, 2);
        ss += __shfl_xor(ss, 4);
        if (sub == 0) inv_s[pxl] = 1.0f / fmaxf(sqrtf(ss), 1e-12f);
    }
    __syncthreads();

    // phase 2: 32 px * 72 float4-chunks, all reads from LDS, coalesced stores
    #pragma unroll 1
    for (int it = 0; it < 9; ++it) {
        int e = it * 256 + tid;
        int pxl = e / 72, dc = e - pxl * 72;
        int l = l0 + pxl;
        float inv = inv_s[pxl];
        float4 o; float* op = &o.x;
        #pragma unroll
        for (int i = 0; i < 4; ++i) {
            int d = dc * 4 + i;
            int c = d / 9, rm = d - c * 9;
            int u = rm / 3, v = rm - u * 3;
            op[i] = tile[u][c][pxl + v] * inv;
        }
        *(float4*)(o32 + (size_t)l * D9 + dc * 4) = o;
        unsigned short b4[4];
        #pragma unroll
        for (int i = 0; i < 4; ++i) b4[i] = f2bf(op[i]);
        *(uint2*)(obf + (size_t)l * D9 + dc * 4) = *(uint2*)b4;
    }
}

// ---------------- MFMA similarity + med3-packed streaming top-6 per key-split ----------------
// Output: query-major packed floats [q][split*NK + s]; key = split*288 + (bits & 0x1FF).
__global__ __launch_bounds__(256, 2) void topk_mfma_kernel(
    const unsigned short* __restrict__ qn_bf, const unsigned short* __restrict__ kn_bf,
    float* __restrict__ valsQ)
{
    __shared__ unsigned short ks[2][32 * KROW];

    int tid  = threadIdx.x;
    int lane = tid & 63;
    int col = lane & 31, khalf = lane >> 5;
    int qtile = blockIdx.x >> 5;
    int split = blockIdx.x & 31;
    int q0w = qtile * 256 + (tid >> 6) * 64;
    int key0 = split * KEYS_PER_SPLIT;

    short8 qf[2][18];
    #pragma unroll
    for (int b = 0; b < 2; ++b) {
        const unsigned short* qrow = qn_bf + (size_t)(q0w + b*32 + col) * D9 + khalf * 8;
        #pragma unroll
        for (int dg = 0; dg < 18; ++dg)
            qf[b][dg] = *(const short8*)(qrow + dg * 16);
    }

    float lv0[NK], lv1[NK];
    #pragma unroll
    for (int s = 0; s < NK; ++s) { lv0[s] = -INFINITY; lv1[s] = -INFINITY; }

    const char* kg = (const char*)kn_bf;
    uint4 pre[5];

    #pragma unroll
    for (int c0 = 0; c0 < 5; ++c0) {
        int c = tid + c0 * 256;
        if (c < CHUNKS) {
            int key = c / 36, off = c - key * 36;
            pre[c0] = *(const uint4*)(kg + (size_t)(key0 + key) * 576 + off * 16);
        }
    }
    #pragma unroll
    for (int c0 = 0; c0 < 5; ++c0) {
        int c = tid + c0 * 256;
        if (c < CHUNKS) {
            int key = c / 36, off = c - key * 36;
            char* d = (char*)ks[0] + key * (KROW*2) + off * 16;
            *(uint2*)d       = *(uint2*)&pre[c0];
            *(uint2*)(d + 8) = *((uint2*)&pre[c0] + 1);
        }
    }
    __syncthreads();

    for (int p = 0; p < PASSES; ++p) {
        if (p + 1 < PASSES) {
            #pragma unroll
            for (int c0 = 0; c0 < 5; ++c0) {
                int c = tid + c0 * 256;
                if (c < CHUNKS) {
                    int key = c / 36, off = c - key * 36;
                    pre[c0] = *(const uint4*)(kg + (size_t)(key0 + (p+1)*32 + key) * 576 + off * 16);
                }
            }
        }

        f32x16 acc0 = {}, acc1 = {};
        const char* kb = (const char*)ks[p & 1] + (size_t)col * (KROW*2) + khalf * 16;
        #pragma unroll
        for (int dg = 0; dg < 18; ++dg) {
            short8 af;
            *(uint2*)&af       = *(const uint2*)(kb + dg * 32);
            *((uint2*)&af + 1) = *(const uint2*)(kb + dg * 32 + 8);
            acc0 = __builtin_amdgcn_mfma_f32_32x32x16_bf16(af, qf[0][dg], acc0, 0, 0, 0);
            acc1 = __builtin_amdgcn_mfma_f32_32x32x16_bf16(af, qf[1][dg], acc1, 0, 0, 0);
        }

        // unconditional med3-network insert of packed (score & ~0x1FF) | local_key
        int lbase = p * 32 + 4 * khalf;
        #pragma unroll
        for (int r = 0; r < 16; ++r) {
            unsigned lkey = (unsigned)(lbase + (r & 3) + 8 * (r >> 2));
            ins_med3<NK>(lv0, asf((asu(acc0[r]) & 0xFFFFFE00u) | lkey));
            ins_med3<NK>(lv1, asf((asu(acc1[r]) & 0xFFFFFE00u) | lkey));
        }

        if (p + 1 < PASSES) {
            #pragma unroll
            for (int c0 = 0; c0 < 5; ++c0) {
                int c = tid + c0 * 256;
                if (c < CHUNKS) {
                    int key = c / 36, off = c - key * 36;
                    char* d = (char*)ks[(p+1) & 1] + key * (KROW*2) + off * 16;
                    *(uint2*)d       = *(uint2*)&pre[c0];
                    *(uint2*)(d + 8) = *((uint2*)&pre[c0] + 1);
                }
            }
        }
        __syncthreads();
    }

    // merge lane pair (lane, lane^32): same query, disjoint keys; write packed
    #pragma unroll
    for (int b = 0; b < 2; ++b) {
        float* lv = b ? lv1 : lv0;
        float pv[NK];
        #pragma unroll
        for (int s = 0; s < NK; ++s) pv[s] = __shfl_xor(lv[s], 32);
        #pragma unroll
        for (int s = 0; s < NK; ++s) ins_med3<NK>(lv, pv[s]);
        if (lane < 32) {
            int q = q0w + b * 32 + col;
            float* vq = valsQ + (size_t)q * CPQ + split * NK;
            #pragma unroll
            for (int s = 0; s < NK; ++s) vq[s] = lv[s];
        }
    }
}

// -------- 32 lanes/query: packed merge -> top-8 candidates -> exact fp32 re-rank --------
__global__ __launch_bounds__(256) void rerank_kernel(
    const float* __restrict__ valsQ,
    const float* __restrict__ qn_f32, const float* __restrict__ kn_f32,
    float* __restrict__ vals, int* __restrict__ idxs)
{
    int tid = threadIdx.x;
    int lane = tid & 63;
    int half = lane >> 5, l32 = lane & 31;
    int q = blockIdx.x * 8 + (tid >> 6) * 2 + half;

    const float* vq = valsQ + (size_t)q * CPQ + l32 * NK;
    float v[NK];
    #pragma unroll
    for (int s = 0; s < NK; ++s) v[s] = vq[s];

    // 8 rounds of wave-parallel argmax over the 32 list heads
    int ckey[NCAND];
    #pragma unroll
    for (int it = 0; it < NCAND; ++it) {
        float cv = v[0];
        int cl = l32;
        #pragma unroll
        for (int st = 1; st < 32; st <<= 1) {
            float ov = __shfl_xor(cv, st);
            int ol = __shfl_xor(cl, st);
            if (ov > cv || (ov == cv && ol < cl)) { cv = ov; cl = ol; }
        }
        ckey[it] = cl * KEYS_PER_SPLIT + (int)(asu(cv) & 0x1FFu);
        if (cl == l32) {                          // winner pops its head
            #pragma unroll
            for (int s = 0; s < NK-1; ++s) v[s] = v[s+1];
            v[NK-1] = -INFINITY;
        }
    }

    // exact fp32 dot: 4 lanes per candidate
    int r = l32 >> 2, part = l32 & 3;
    const float4* qr = (const float4*)(qn_f32 + (size_t)q * D9) + part * 18;
    const float4* kr = (const float4*)(kn_f32 + (size_t)ckey[r] * D9) + part * 18;
    float s0 = 0.f, s1 = 0.f, s2 = 0.f, s3 = 0.f;
    #pragma unroll
    for (int i2 = 0; i2 < 18; ++i2) {
        float4 a = qr[i2], b = kr[i2];
        s0 = fmaf(a.x, b.x, s0); s1 = fmaf(a.y, b.y, s1);
        s2 = fmaf(a.z, b.z, s2); s3 = fmaf(a.w, b.w, s3);
    }
    float sc = (s0 + s1) + (s2 + s3);
    sc += __shfl_xor(sc, 1);
    sc += __shfl_xor(sc, 2);

    // top-5 with exact scores + lax.top_k tie-break
    float bv[TOPK]; int bi[TOPK];
    #pragma unroll
    for (int s = 0; s < TOPK; ++s) { bv[s] = -INFINITY; bi[s] = 0x7fffffff; }
    #pragma unroll
    for (int cc = 0; cc < NCAND; ++cc) {
        float sv = __shfl(sc, half * 32 + cc * 4);
        insert_tb<TOPK>(bv, bi, sv, ckey[cc]);
    }
    if (l32 == 0) {
        #pragma unroll
        for (int s = 0; s < TOPK; ++s) {
            vals[(size_t)s * LL + q] = bv[s];
            idxs[(size_t)s * LL + q] = bi[s];
        }
    }
}

// ------------- epilogue: wave-per-pixel, lanes over channels, coalesced gathers -------------
__global__ __launch_bounds__(256) void gather_out_kernel(
    const float* __restrict__ xT, const float* __restrict__ feat,
    const float* __restrict__ vals, const int* __restrict__ idxs,
    float* __restrict__ out)
{
    int wave = threadIdx.x >> 6, lane = threadIdx.x & 63;
    int pix = blockIdx.x * 4 + wave;
    int y = pix / WW, x0 = pix - y * WW;
    float acc = 0.0f;
    #pragma unroll 1
    for (int s = 1; s < TOPK; ++s) {
        float S = vals[(size_t)s * LL + pix] * (1.0f/9.0f);
        #pragma unroll
        for (int i = 0; i < 3; ++i) {
            int qy = y + 1 - i;
            #pragma unroll
            for (int j = 0; j < 3; ++j) {
                int qx = x0 + 1 - j;
                if ((unsigned)qy < 96u && (unsigned)qx < 96u) {   // wave-uniform
                    int l = idxs[(size_t)s * LL + qy * WW + qx];  // broadcast
                    int yl = l / WW, xl = l - yl * WW;
                    int sy = yl + i - 1, sx = xl + j - 1;
                    if ((unsigned)sy < 96u && (unsigned)sx < 96u) // wave-uniform
                        acc = fmaf(S, xT[(size_t)(sy * WW + sx) * 64 + lane], acc);
                }
            }
        }
    }
    out[(size_t)lane * LL + pix] = feat[(size_t)lane * LL + pix]
                                 + xT[(size_t)pix * 64 + lane] + acc * 0.25f;
}

extern "C" void kernel_launch(void* const* d_in, const int* in_sizes, int n_in,
                              void* d_out, int out_size, void* d_ws, size_t ws_size,
                              hipStream_t stream)
{
    (void)in_sizes; (void)n_in; (void)out_size; (void)ws_size;
    const float* x  = (const float*)d_in[0];
    const float* W1 = (const float*)d_in[1];
    const float* b1 = (const float*)d_in[2];
    const float* W2 = (const float*)d_in[3];
    const float* b2 = (const float*)d_in[4];
    const float* Wq = (const float*)d_in[5];
    const float* bq = (const float*)d_in[6];
    const float* Wk = (const float*)d_in[7];
    const float* bk = (const float*)d_in[8];
    float* out = (float*)d_out;

    char* p = (char*)d_ws;
    float* c1     = (float*)p;            p += (size_t)64 * LL * 4;
    float* feat   = (float*)p;            p += (size_t)64 * LL * 4;
    float* xT     = (float*)p;            p += (size_t)64 * LL * 4;
    float* qq     = (float*)p;            p += (size_t)32 * LL * 4;
    float* kk     = (float*)p;            p += (size_t)32 * LL * 4;
    float* qn_f32 = (float*)p;            p += (size_t)LL * D9 * 4;
    float* kn_f32 = (float*)p;            p += (size_t)LL * D9 * 4;
    unsigned short* qn_bf = (unsigned short*)p;  p += (size_t)LL * D9 * 2;
    unsigned short* kn_bf = (unsigned short*)p;  p += (size_t)LL * D9 * 2;
    float* valsQ  = (float*)p;            p += (size_t)LL * CPQ * 4;
    float* vals   = (float*)p;            p += (size_t)TOPK * LL * 4;
    int*   idxs   = (int*)p;              p += (size_t)TOPK * LL * 4;

    conv_stage1_kernel<<<dim3(36, 24), 256, 0, stream>>>(x, W1, b1, c1, Wq, bq, Wk, bk, qq, kk);
    unfold_norm_kernel<<<dim3(288, 2), 256, 0, stream>>>(qq, qn_f32, qn_bf, kk, kn_f32, kn_bf);
    topk_mfma_kernel<<<36 * KSPLIT, 256, 0, stream>>>(qn_bf, kn_bf, valsQ);
    conv3_co4_kernel<<<dim3(36, 16), 256, 0, stream>>>(c1, W2, b2, feat);
    transpose_x_kernel<<<144, 256, 0, stream>>>(x, xT);
    rerank_kernel<<<LL / 8, 256, 0, stream>>>(valsQ, qn_f32, kn_f32, vals, idxs);
    gather_out_kernel<<<LL / 4, 256, 0, stream>>>(xT, feat, vals, idxs, out);
}